// Round 3
// baseline (11894.450 us; speedup 1.0000x reference)
//
#include <hip/hip_runtime.h>
#include <math.h>

#define BATCH 1024
#define IN_F  1024
#define OUT_F 2048
#define LAMBD 0.2f
#define TOL   1e-4f
#define MAX_ITERS 100

typedef _Float16 half8 __attribute__((ext_vector_type(8)));
typedef _Float16 half4 __attribute__((ext_vector_type(4)));
typedef float    floatx16 __attribute__((ext_vector_type(16)));

#define GLOAD_LDS16(g, l) __builtin_amdgcn_global_load_lds(              \
    (const __attribute__((address_space(1))) void*)(g),                  \
    (__attribute__((address_space(3))) void*)(l), 16, 0, 0)

// fp32 fallback GEMM tiling (one-shot GEMMs)
#define BM 64
#define BN 64
#define BK 16
#define TM 4
#define TN 4
#define LDA (BM + 4)
#define LDB (BN + 4)

// ---------------------------------------------------------------------------
__global__ void init_kernel(float4* __restrict__ v, float4* __restrict__ u,
                            float4* __restrict__ enc, int* __restrict__ solved,
                            float* __restrict__ dxa, float* __restrict__ xna) {
    const int i = blockIdx.x * blockDim.x + threadIdx.x;
    const int n4 = BATCH * OUT_F / 4;
    const float4 z = make_float4(0.f, 0.f, 0.f, 0.f);
    if (i < n4) { v[i] = z; u[i] = z; enc[i] = z; }
    if (i < BATCH) { solved[i] = 0; dxa[i] = 0.f; xna[i] = 0.f; }
}

// ---------------------------------------------------------------------------
// Split + transpose M_inv (2048x2048 fp32 [k][n]) -> BhT/BlT fp16 [n][k].
// ---------------------------------------------------------------------------
__global__ __launch_bounds__(256)
void split_b_kernel(const float* __restrict__ B, _Float16* __restrict__ BhT,
                    _Float16* __restrict__ BlT) {
    __shared__ float tile[32][33];
    const int tid = threadIdx.x;
    const int k0 = blockIdx.y * 32;
    const int n0 = blockIdx.x * 32;
    const int r = tid >> 3;
    const int c4 = (tid & 7) * 4;
    const float4 b4 = *(const float4*)&B[(size_t)(k0 + r) * OUT_F + n0 + c4];
    tile[r][c4 + 0] = b4.x; tile[r][c4 + 1] = b4.y;
    tile[r][c4 + 2] = b4.z; tile[r][c4 + 3] = b4.w;
    __syncthreads();
    half4 h, l;
#pragma unroll
    for (int j = 0; j < 4; ++j) {
        const float x = tile[c4 + j][r];
        const _Float16 hi = (_Float16)x;
        h[j] = hi;
        l[j] = (_Float16)(x - (float)hi);
    }
    const size_t o = (size_t)(n0 + r) * OUT_F + k0 + c4;
    *(half4*)&BhT[o] = h;
    *(half4*)&BlT[o] = l;
}

// ---------------------------------------------------------------------------
// NT GEMM fp32: Ab = x @ w^T, epilogue writes initial Aeff split (v=u=0).
// ---------------------------------------------------------------------------
__global__ __launch_bounds__(256)
void gemm_nt(const float* __restrict__ A, const float* __restrict__ B,
             float* __restrict__ C, _Float16* __restrict__ Ah,
             _Float16* __restrict__ Al, int M, int N, int K) {
    __shared__ float As[BK][LDA];
    __shared__ float Bs[BK][LDB];
    const int tid = threadIdx.x;
    const int tx = tid & 15, ty = tid >> 4;
    const int m0 = blockIdx.y * BM;
    const int n0 = blockIdx.x * BN;
    const int lr = tid >> 2;
    const int lk = (tid & 3) * 4;

    float acc[TM][TN] = {};

    for (int k0 = 0; k0 < K; k0 += BK) {
        const float4 a4 = *(const float4*)&A[(size_t)(m0 + lr) * K + k0 + lk];
        const float4 b4 = *(const float4*)&B[(size_t)(n0 + lr) * K + k0 + lk];
        __syncthreads();
        As[lk + 0][lr] = a4.x; As[lk + 1][lr] = a4.y; As[lk + 2][lr] = a4.z; As[lk + 3][lr] = a4.w;
        Bs[lk + 0][lr] = b4.x; Bs[lk + 1][lr] = b4.y; Bs[lk + 2][lr] = b4.z; Bs[lk + 3][lr] = b4.w;
        __syncthreads();
#pragma unroll
        for (int kk = 0; kk < BK; ++kk) {
            const float4 av = *(const float4*)&As[kk][ty * TM];
            const float4 bv = *(const float4*)&Bs[kk][tx * TN];
            const float ar[4] = {av.x, av.y, av.z, av.w};
            const float br[4] = {bv.x, bv.y, bv.z, bv.w};
#pragma unroll
            for (int i = 0; i < TM; ++i)
#pragma unroll
                for (int j = 0; j < TN; ++j)
                    acc[i][j] = fmaf(ar[i], br[j], acc[i][j]);
        }
    }
#pragma unroll
    for (int i = 0; i < TM; ++i) {
        const size_t o = (size_t)(m0 + ty * TM + i) * N + n0 + tx * TN;
        *(float4*)&C[o] = make_float4(acc[i][0], acc[i][1], acc[i][2], acc[i][3]);
        half4 h, l;
#pragma unroll
        for (int j = 0; j < 4; ++j) {
            const float xv = acc[i][j];
            const _Float16 hi = (_Float16)xv;
            h[j] = hi;
            l[j] = (_Float16)(xv - (float)hi);
        }
        *(half4*)&Ah[o] = h;
        *(half4*)&Al[o] = l;
    }
}

// ---------------------------------------------------------------------------
// Fused iteration kernel: full-K split-fp16 MFMA GEMM (tile 64x128, KSPLIT=1)
// + in-epilogue softshrink/u-update/Aeff-split + per-row norm atomics.
// Grid (16 N, 16 M) = 256 blocks, 256 threads (4 waves of 32x64).
// ---------------------------------------------------------------------------
__global__ __launch_bounds__(256)
void xk_fused(const _Float16* __restrict__ Ahi, const _Float16* __restrict__ Alo,
              const _Float16* __restrict__ BhT, const _Float16* __restrict__ BlT,
              const float* __restrict__ Ab, float* __restrict__ v,
              float* __restrict__ u, _Float16* __restrict__ AhO,
              _Float16* __restrict__ AlO, float* __restrict__ dxa,
              float* __restrict__ xna, const int* __restrict__ solved) {
    __shared__ _Float16 sAh[64 * 16];
    __shared__ _Float16 sAl[64 * 16];
    __shared__ _Float16 sBh[128 * 16];
    __shared__ _Float16 sBl[128 * 16];
    __shared__ int s_sol[64];
    __shared__ int s_active;

    const int tid = threadIdx.x;
    const int m0 = blockIdx.y * 64;
    const int n0 = blockIdx.x * 128;

    if (tid == 0) s_active = 0;
    if (tid < 64) s_sol[tid] = solved[m0 + tid];
    __syncthreads();
    if (tid < 64 && s_sol[tid] == 0) s_active = 1;   // benign race
    __syncthreads();
    if (!s_active) return;                            // whole 64-row strip frozen

    const int wv = tid >> 6;
    const int ln = tid & 63;
    const int half = ln >> 5;
    const int l31 = ln & 31;
    const int wm = (wv >> 1) * 32;    // wave row base within 64
    const int wnl = (wv & 1) * 64;    // wave col base within 128

    // staging addresses
    const int ta = tid & 127;
    const _Float16* gA = (tid < 128 ? Ahi : Alo) +
                         (size_t)(m0 + (ta >> 1)) * OUT_F + (ta & 1) * 8;
    _Float16* sA_dst = (tid < 128 ? sAh : sAl) + ta * 8;
    const size_t boff = (size_t)(n0 + (tid >> 1)) * OUT_F + (tid & 1) * 8;
    const _Float16* gBh = BhT + boff;
    const _Float16* gBl = BlT + boff;
    _Float16* sBh_dst = sBh + tid * 8;
    _Float16* sBl_dst = sBl + tid * 8;

    floatx16 acc[2];
#pragma unroll
    for (int nn = 0; nn < 2; ++nn)
#pragma unroll
        for (int r = 0; r < 16; ++r) acc[nn][r] = 0.f;

    for (int k = 0; k < OUT_F; k += 16) {
        __syncthreads();
        GLOAD_LDS16(gBh + k, sBh_dst);
        GLOAD_LDS16(gBl + k, sBl_dst);
        GLOAD_LDS16(gA + k, sA_dst);
        __syncthreads();

        const half8 ah  = *(const half8*)&sAh[(wm + l31) * 16 + half * 8];
        const half8 al  = *(const half8*)&sAl[(wm + l31) * 16 + half * 8];
        const half8 bh0 = *(const half8*)&sBh[(wnl + l31) * 16 + half * 8];
        const half8 bh1 = *(const half8*)&sBh[(wnl + 32 + l31) * 16 + half * 8];
        const half8 bl0 = *(const half8*)&sBl[(wnl + l31) * 16 + half * 8];
        const half8 bl1 = *(const half8*)&sBl[(wnl + 32 + l31) * 16 + half * 8];

        acc[0] = __builtin_amdgcn_mfma_f32_32x32x16_f16(ah, bh0, acc[0], 0, 0, 0);
        acc[1] = __builtin_amdgcn_mfma_f32_32x32x16_f16(ah, bh1, acc[1], 0, 0, 0);
        acc[0] = __builtin_amdgcn_mfma_f32_32x32x16_f16(ah, bl0, acc[0], 0, 0, 0);
        acc[1] = __builtin_amdgcn_mfma_f32_32x32x16_f16(ah, bl1, acc[1], 0, 0, 0);
        acc[0] = __builtin_amdgcn_mfma_f32_32x32x16_f16(al, bh0, acc[0], 0, 0, 0);
        acc[1] = __builtin_amdgcn_mfma_f32_32x32x16_f16(al, bh1, acc[1], 0, 0, 0);
    }

    // -------- fused epilogue: softshrink + u update + Aeff split + row norms
#pragma unroll
    for (int nn = 0; nn < 2; ++nn) {
        const int col = n0 + wnl + nn * 32 + l31;
#pragma unroll
        for (int r = 0; r < 16; ++r) {
            const int lrow = wm + (r & 3) + 8 * (r >> 2) + 4 * half;  // 0..63
            const int frozen = s_sol[lrow];   // uniform across l31 within half
            float d2 = 0.f, n2 = 0.f;
            if (!frozen) {
                const int row = m0 + lrow;
                const size_t o = (size_t)row * OUT_F + col;
                const float xk = acc[nn][r];
                const float uv = u[o];
                const float vp = v[o];
                const float ab = Ab[o];
                const float z = xk + uv;
                const float az = fabsf(z) - LAMBD;
                const float vnew = az > 0.f ? copysignf(az, z) : 0.f;
                const float unew = uv + xk - vnew;
                v[o] = vnew;
                u[o] = unew;
                const float aeff = ab + vnew - unew;
                const _Float16 hi = (_Float16)aeff;
                AhO[o] = hi;
                AlO[o] = (_Float16)(aeff - (float)hi);
                const float d = vnew - vp;
                d2 = d * d;
                n2 = vnew * vnew;
                // 32-lane butterfly (stays within each half for masks<=16)
#pragma unroll
                for (int msk = 16; msk > 0; msk >>= 1) {
                    d2 += __shfl_xor(d2, msk);
                    n2 += __shfl_xor(n2, msk);
                }
                if (l31 == 0) {
                    atomicAdd(&dxa[row], d2);
                    atomicAdd(&xna[row], n2);
                }
            }
        }
    }
}

// ---------------------------------------------------------------------------
// Per-row convergence decision + accumulator reset + enc emit on convergence.
// 4 blocks x 256 threads (one thread per row).
// ---------------------------------------------------------------------------
__global__ __launch_bounds__(256)
void conv_kernel(float* __restrict__ dxa, float* __restrict__ xna,
                 const float* __restrict__ v, float* __restrict__ enc,
                 int* __restrict__ solved) {
    __shared__ unsigned char s_newly[256];
    const int t = threadIdx.x;
    const int row = blockIdx.x * 256 + t;
    int newly = 0;
    if (!solved[row]) {
        const float dxt = sqrtf(dxa[row]);
        const float xnt = sqrtf(xna[row]);
        if (dxt / xnt < TOL) {    // NaN/inf -> false, matches jnp
            newly = 1;
            solved[row] = 1;
        }
    }
    dxa[row] = 0.f;
    xna[row] = 0.f;
    s_newly[t] = (unsigned char)newly;
    __syncthreads();
    for (int i = 0; i < 256; ++i) {
        if (s_newly[i]) {
            const int r2 = blockIdx.x * 256 + i;
            const float4* src = (const float4*)&v[(size_t)r2 * OUT_F];
            float4* dst = (float4*)&enc[(size_t)r2 * OUT_F];
            for (int c = t; c < OUT_F / 4; c += 256) dst[c] = src[c];
        }
    }
}

// ---------------------------------------------------------------------------
// Plain NN GEMM fp32: decoded = encoded @ w  (one-shot)
// ---------------------------------------------------------------------------
__global__ __launch_bounds__(256)
void gemm_nn(const float* __restrict__ A, const float* __restrict__ B,
             float* __restrict__ C, int M, int N, int K) {
    __shared__ float As[BK][LDA];
    __shared__ float Bs[BK][LDB];
    const int tid = threadIdx.x;
    const int tx = tid & 15, ty = tid >> 4;
    const int m0 = blockIdx.y * BM;
    const int n0 = blockIdx.x * BN;
    const int lr = tid >> 2;
    const int lk = (tid & 3) * 4;
    const int kb = tid >> 4;
    const int nb = (tid & 15) * 4;

    float acc[TM][TN] = {};

    for (int k0 = 0; k0 < K; k0 += BK) {
        const float4 a4 = *(const float4*)&A[(size_t)(m0 + lr) * K + k0 + lk];
        const float4 b4 = *(const float4*)&B[(size_t)(k0 + kb) * N + n0 + nb];
        __syncthreads();
        As[lk + 0][lr] = a4.x; As[lk + 1][lr] = a4.y; As[lk + 2][lr] = a4.z; As[lk + 3][lr] = a4.w;
        *(float4*)&Bs[kb][nb] = b4;
        __syncthreads();
#pragma unroll
        for (int kk = 0; kk < BK; ++kk) {
            const float4 av = *(const float4*)&As[kk][ty * TM];
            const float4 bv = *(const float4*)&Bs[kk][tx * TN];
            const float ar[4] = {av.x, av.y, av.z, av.w};
            const float br[4] = {bv.x, bv.y, bv.z, bv.w};
#pragma unroll
            for (int i = 0; i < TM; ++i)
#pragma unroll
                for (int j = 0; j < TN; ++j)
                    acc[i][j] = fmaf(ar[i], br[j], acc[i][j]);
        }
    }
#pragma unroll
    for (int i = 0; i < TM; ++i) {
        float4 o = make_float4(acc[i][0], acc[i][1], acc[i][2], acc[i][3]);
        *(float4*)&C[(size_t)(m0 + ty * TM + i) * N + n0 + tx * TN] = o;
    }
}

// ---------------------------------------------------------------------------
extern "C" void kernel_launch(void* const* d_in, const int* in_sizes, int n_in,
                              void* d_out, int out_size, void* d_ws, size_t ws_size,
                              hipStream_t stream) {
    (void)in_sizes; (void)n_in; (void)out_size; (void)ws_size;
    const float* x    = (const float*)d_in[0];   // 1024 x 1024
    const float* w    = (const float*)d_in[1];   // 2048 x 1024
    const float* Minv = (const float*)d_in[2];   // 2048 x 2048

    float* enc = (float*)d_out;                  // 1024 x 2048
    float* dec = enc + (size_t)BATCH * OUT_F;    // 1024 x 1024

    constexpr size_t P = (size_t)BATCH * OUT_F;  // 2M elements
    float* Ab  = (float*)d_ws;                   // 2M f32
    float* v   = Ab + P;
    float* u   = v + P;
    float* dxa = u + P;                          // 1024 f32
    float* xna = dxa + BATCH;                    // 1024 f32
    _Float16* Ah0 = (_Float16*)(xna + BATCH);    // 2M f16 (ping)
    _Float16* Al0 = Ah0 + P;
    _Float16* Ah1 = Al0 + P;                     // 2M f16 (pong)
    _Float16* Al1 = Ah1 + P;
    _Float16* BhT = Al1 + P;                     // 4M f16
    _Float16* BlT = BhT + (size_t)OUT_F * OUT_F;
    int* solved = (int*)(BlT + (size_t)OUT_F * OUT_F);

    {
        const int n4 = BATCH * OUT_F / 4;
        init_kernel<<<(n4 + 255) / 256, 256, 0, stream>>>(
            (float4*)v, (float4*)u, (float4*)enc, solved, dxa, xna);
    }

    split_b_kernel<<<dim3(OUT_F / 32, OUT_F / 32), 256, 0, stream>>>(Minv, BhT, BlT);

    gemm_nt<<<dim3(OUT_F / BN, BATCH / BM), 256, 0, stream>>>(x, w, Ab, Ah0, Al0,
                                                              BATCH, OUT_F, IN_F);

    for (int it = 0; it < MAX_ITERS; ++it) {
        const _Float16* Ai_h = (it & 1) ? Ah1 : Ah0;
        const _Float16* Ai_l = (it & 1) ? Al1 : Al0;
        _Float16* Ao_h = (it & 1) ? Ah0 : Ah1;
        _Float16* Ao_l = (it & 1) ? Al0 : Al1;
        xk_fused<<<dim3(OUT_F / 128, BATCH / 64), 256, 0, stream>>>(
            Ai_h, Ai_l, BhT, BlT, Ab, v, u, Ao_h, Ao_l, dxa, xna, solved);
        conv_kernel<<<BATCH / 256, 256, 0, stream>>>(dxa, xna, v, enc, solved);
    }

    gemm_nn<<<dim3(IN_F / BN, BATCH / BM), 256, 0, stream>>>(enc, w, dec, BATCH, IN_F, OUT_F);
}

// Round 4
// 6409.367 us; speedup vs baseline: 1.8558x; 1.8558x over previous
//
#include <hip/hip_runtime.h>
#include <math.h>

#define BATCH 1024
#define IN_F  1024
#define OUT_F 2048
#define LAMBD 0.2f
#define TOL   1e-4f
#define MAX_ITERS 100

#define KSPLIT 2
#define KCHUNK (OUT_F / KSPLIT)   // 1024

typedef _Float16 half8 __attribute__((ext_vector_type(8)));
typedef _Float16 half4 __attribute__((ext_vector_type(4)));
typedef float    floatx16 __attribute__((ext_vector_type(16)));

#define GLOAD_LDS16(g, l) __builtin_amdgcn_global_load_lds(              \
    (const __attribute__((address_space(1))) void*)(g),                  \
    (__attribute__((address_space(3))) void*)(l), 16, 0, 0)

// fp32 fallback GEMM tiling (one-shot GEMMs)
#define BM 64
#define BN 64
#define BK 16
#define TM 4
#define TN 4
#define LDA (BM + 4)
#define LDB (BN + 4)

// ---------------------------------------------------------------------------
__global__ void init_kernel(float4* __restrict__ v, float4* __restrict__ u,
                            float4* __restrict__ enc, int* __restrict__ solved) {
    const int i = blockIdx.x * blockDim.x + threadIdx.x;
    const int n4 = BATCH * OUT_F / 4;
    const float4 z = make_float4(0.f, 0.f, 0.f, 0.f);
    if (i < n4) { v[i] = z; u[i] = z; enc[i] = z; }
    if (i < BATCH) solved[i] = 0;
}

// ---------------------------------------------------------------------------
// Split + transpose M_inv (2048x2048 fp32 [k][n]) -> BhT/BlT fp16 [n][k].
// ---------------------------------------------------------------------------
__global__ __launch_bounds__(256)
void split_b_kernel(const float* __restrict__ B, _Float16* __restrict__ BhT,
                    _Float16* __restrict__ BlT) {
    __shared__ float tile[32][33];
    const int tid = threadIdx.x;
    const int k0 = blockIdx.y * 32;
    const int n0 = blockIdx.x * 32;
    const int r = tid >> 3;
    const int c4 = (tid & 7) * 4;
    const float4 b4 = *(const float4*)&B[(size_t)(k0 + r) * OUT_F + n0 + c4];
    tile[r][c4 + 0] = b4.x; tile[r][c4 + 1] = b4.y;
    tile[r][c4 + 2] = b4.z; tile[r][c4 + 3] = b4.w;
    __syncthreads();
    half4 h, l;
#pragma unroll
    for (int j = 0; j < 4; ++j) {
        const float x = tile[c4 + j][r];
        const _Float16 hi = (_Float16)x;
        h[j] = hi;
        l[j] = (_Float16)(x - (float)hi);
    }
    const size_t o = (size_t)(n0 + r) * OUT_F + k0 + c4;
    *(half4*)&BhT[o] = h;
    *(half4*)&BlT[o] = l;
}

// ---------------------------------------------------------------------------
// NT GEMM fp32: Ab = x @ w^T, epilogue writes initial Aeff split (v=u=0).
// ---------------------------------------------------------------------------
__global__ __launch_bounds__(256)
void gemm_nt(const float* __restrict__ A, const float* __restrict__ B,
             float* __restrict__ C, _Float16* __restrict__ Ah,
             _Float16* __restrict__ Al, int M, int N, int K) {
    __shared__ float As[BK][LDA];
    __shared__ float Bs[BK][LDB];
    const int tid = threadIdx.x;
    const int tx = tid & 15, ty = tid >> 4;
    const int m0 = blockIdx.y * BM;
    const int n0 = blockIdx.x * BN;
    const int lr = tid >> 2;
    const int lk = (tid & 3) * 4;

    float acc[TM][TN] = {};

    for (int k0 = 0; k0 < K; k0 += BK) {
        const float4 a4 = *(const float4*)&A[(size_t)(m0 + lr) * K + k0 + lk];
        const float4 b4 = *(const float4*)&B[(size_t)(n0 + lr) * K + k0 + lk];
        __syncthreads();
        As[lk + 0][lr] = a4.x; As[lk + 1][lr] = a4.y; As[lk + 2][lr] = a4.z; As[lk + 3][lr] = a4.w;
        Bs[lk + 0][lr] = b4.x; Bs[lk + 1][lr] = b4.y; Bs[lk + 2][lr] = b4.z; Bs[lk + 3][lr] = b4.w;
        __syncthreads();
#pragma unroll
        for (int kk = 0; kk < BK; ++kk) {
            const float4 av = *(const float4*)&As[kk][ty * TM];
            const float4 bv = *(const float4*)&Bs[kk][tx * TN];
            const float ar[4] = {av.x, av.y, av.z, av.w};
            const float br[4] = {bv.x, bv.y, bv.z, bv.w};
#pragma unroll
            for (int i = 0; i < TM; ++i)
#pragma unroll
                for (int j = 0; j < TN; ++j)
                    acc[i][j] = fmaf(ar[i], br[j], acc[i][j]);
        }
    }
#pragma unroll
    for (int i = 0; i < TM; ++i) {
        const size_t o = (size_t)(m0 + ty * TM + i) * N + n0 + tx * TN;
        *(float4*)&C[o] = make_float4(acc[i][0], acc[i][1], acc[i][2], acc[i][3]);
        half4 h, l;
#pragma unroll
        for (int j = 0; j < 4; ++j) {
            const float xv = acc[i][j];
            const _Float16 hi = (_Float16)xv;
            h[j] = hi;
            l[j] = (_Float16)(xv - (float)hi);
        }
        *(half4*)&Ah[o] = h;
        *(half4*)&Al[o] = l;
    }
}

// ---------------------------------------------------------------------------
// MFMA split-fp16 GEMM: xk_part[kz] = Aeff[:, kz*1024+...] @ Minv[kz...]
// 128x128 tile, BK=32 (half the barriers of BK=16), 4 waves of 2x2 32x32x16.
// Grid (16, 8, 2) = 256 blocks.
// ---------------------------------------------------------------------------
__global__ __launch_bounds__(256)
void xk_mfma(const _Float16* __restrict__ Ah, const _Float16* __restrict__ Al,
             const _Float16* __restrict__ BhT, const _Float16* __restrict__ BlT,
             float* __restrict__ xkp, const int* __restrict__ solved) {
    __shared__ _Float16 sAh[128 * 32];
    __shared__ _Float16 sAl[128 * 32];
    __shared__ _Float16 sBh[128 * 32];
    __shared__ _Float16 sBl[128 * 32];
    const int tid = threadIdx.x;
    const int m0 = blockIdx.y * 128;
    const int n0 = blockIdx.x * 128;
    const int kz = blockIdx.z;

    __shared__ int s_active;
    if (tid == 0) s_active = 0;
    __syncthreads();
    if (tid < 128 && solved[m0 + tid] == 0) s_active = 1;   // benign race
    __syncthreads();
    if (!s_active) return;

    const int wv = tid >> 6;
    const int ln = tid & 63;
    const int half = ln >> 5;
    const int l31 = ln & 31;
    const int wm = (wv >> 1) * 64;
    const int wn = (wv & 1) * 64;

    // staging: two issues per array per BK-32 step; flat = i*256 + tid
    // row = flat>>2 (0..127), koff = (flat&3)*8
    const int r0 = tid >> 2,        k0off = (tid & 3) * 8;        // i = 0
    const int r1 = (256 + tid) >> 2, k1off = (tid & 3) * 8;       // i = 1 (row += 64)
    const size_t ga0 = (size_t)(m0 + r0) * OUT_F + kz * KCHUNK + k0off;
    const size_t ga1 = (size_t)(m0 + r1) * OUT_F + kz * KCHUNK + k1off;
    const size_t gb0 = (size_t)(n0 + r0) * OUT_F + kz * KCHUNK + k0off;
    const size_t gb1 = (size_t)(n0 + r1) * OUT_F + kz * KCHUNK + k1off;
    _Float16* l0 = (_Float16*)nullptr;
    (void)l0;
    const int ldst0 = tid * 8;          // halves
    const int ldst1 = (256 + tid) * 8;

    floatx16 acc[2][2];
#pragma unroll
    for (int a = 0; a < 2; ++a)
#pragma unroll
        for (int b = 0; b < 2; ++b)
#pragma unroll
            for (int r = 0; r < 16; ++r) acc[a][b][r] = 0.f;

    for (int k = 0; k < KCHUNK; k += 32) {
        __syncthreads();
        GLOAD_LDS16(Ah  + ga0 + k, sAh + ldst0);
        GLOAD_LDS16(Ah  + ga1 + k, sAh + ldst1);
        GLOAD_LDS16(Al  + ga0 + k, sAl + ldst0);
        GLOAD_LDS16(Al  + ga1 + k, sAl + ldst1);
        GLOAD_LDS16(BhT + gb0 + k, sBh + ldst0);
        GLOAD_LDS16(BhT + gb1 + k, sBh + ldst1);
        GLOAD_LDS16(BlT + gb0 + k, sBl + ldst0);
        GLOAD_LDS16(BlT + gb1 + k, sBl + ldst1);
        __syncthreads();

#pragma unroll
        for (int kk = 0; kk < 2; ++kk) {
            const int ko = kk * 16 + half * 8;
            const half8 ah0 = *(const half8*)&sAh[(wm + l31) * 32 + ko];
            const half8 ah1 = *(const half8*)&sAh[(wm + 32 + l31) * 32 + ko];
            const half8 al0 = *(const half8*)&sAl[(wm + l31) * 32 + ko];
            const half8 al1 = *(const half8*)&sAl[(wm + 32 + l31) * 32 + ko];
            const half8 bh0 = *(const half8*)&sBh[(wn + l31) * 32 + ko];
            const half8 bh1 = *(const half8*)&sBh[(wn + 32 + l31) * 32 + ko];
            const half8 bl0 = *(const half8*)&sBl[(wn + l31) * 32 + ko];
            const half8 bl1 = *(const half8*)&sBl[(wn + 32 + l31) * 32 + ko];

            acc[0][0] = __builtin_amdgcn_mfma_f32_32x32x16_f16(ah0, bh0, acc[0][0], 0, 0, 0);
            acc[0][1] = __builtin_amdgcn_mfma_f32_32x32x16_f16(ah0, bh1, acc[0][1], 0, 0, 0);
            acc[1][0] = __builtin_amdgcn_mfma_f32_32x32x16_f16(ah1, bh0, acc[1][0], 0, 0, 0);
            acc[1][1] = __builtin_amdgcn_mfma_f32_32x32x16_f16(ah1, bh1, acc[1][1], 0, 0, 0);
            acc[0][0] = __builtin_amdgcn_mfma_f32_32x32x16_f16(ah0, bl0, acc[0][0], 0, 0, 0);
            acc[0][1] = __builtin_amdgcn_mfma_f32_32x32x16_f16(ah0, bl1, acc[0][1], 0, 0, 0);
            acc[1][0] = __builtin_amdgcn_mfma_f32_32x32x16_f16(ah1, bl0, acc[1][0], 0, 0, 0);
            acc[1][1] = __builtin_amdgcn_mfma_f32_32x32x16_f16(ah1, bl1, acc[1][1], 0, 0, 0);
            acc[0][0] = __builtin_amdgcn_mfma_f32_32x32x16_f16(al0, bh0, acc[0][0], 0, 0, 0);
            acc[0][1] = __builtin_amdgcn_mfma_f32_32x32x16_f16(al0, bh1, acc[0][1], 0, 0, 0);
            acc[1][0] = __builtin_amdgcn_mfma_f32_32x32x16_f16(al1, bh0, acc[1][0], 0, 0, 0);
            acc[1][1] = __builtin_amdgcn_mfma_f32_32x32x16_f16(al1, bh1, acc[1][1], 0, 0, 0);
        }
    }

    float* out = xkp + (size_t)kz * BATCH * OUT_F;
#pragma unroll
    for (int mm = 0; mm < 2; ++mm)
#pragma unroll
        for (int nn = 0; nn < 2; ++nn) {
            const int col = n0 + wn + nn * 32 + l31;
#pragma unroll
            for (int r = 0; r < 16; ++r) {
                const int row = m0 + wm + mm * 32 + (r & 3) + 8 * (r >> 2) + 4 * half;
                out[(size_t)row * OUT_F + col] = acc[mm][nn][r];
            }
        }
}

// ---------------------------------------------------------------------------
// Plain NN GEMM fp32: decoded = encoded @ w  (one-shot)
// ---------------------------------------------------------------------------
__global__ __launch_bounds__(256)
void gemm_nn(const float* __restrict__ A, const float* __restrict__ B,
             float* __restrict__ C, int M, int N, int K) {
    __shared__ float As[BK][LDA];
    __shared__ float Bs[BK][LDB];
    const int tid = threadIdx.x;
    const int tx = tid & 15, ty = tid >> 4;
    const int m0 = blockIdx.y * BM;
    const int n0 = blockIdx.x * BN;
    const int lr = tid >> 2;
    const int lk = (tid & 3) * 4;
    const int kb = tid >> 4;
    const int nb = (tid & 15) * 4;

    float acc[TM][TN] = {};

    for (int k0 = 0; k0 < K; k0 += BK) {
        const float4 a4 = *(const float4*)&A[(size_t)(m0 + lr) * K + k0 + lk];
        const float4 b4 = *(const float4*)&B[(size_t)(k0 + kb) * N + n0 + nb];
        __syncthreads();
        As[lk + 0][lr] = a4.x; As[lk + 1][lr] = a4.y; As[lk + 2][lr] = a4.z; As[lk + 3][lr] = a4.w;
        *(float4*)&Bs[kb][nb] = b4;
        __syncthreads();
#pragma unroll
        for (int kk = 0; kk < BK; ++kk) {
            const float4 av = *(const float4*)&As[kk][ty * TM];
            const float4 bv = *(const float4*)&Bs[kk][tx * TN];
            const float ar[4] = {av.x, av.y, av.z, av.w};
            const float br[4] = {bv.x, bv.y, bv.z, bv.w};
#pragma unroll
            for (int i = 0; i < TM; ++i)
#pragma unroll
                for (int j = 0; j < TN; ++j)
                    acc[i][j] = fmaf(ar[i], br[j], acc[i][j]);
        }
    }
#pragma unroll
    for (int i = 0; i < TM; ++i) {
        float4 o = make_float4(acc[i][0], acc[i][1], acc[i][2], acc[i][3]);
        *(float4*)&C[(size_t)(m0 + ty * TM + i) * N + n0 + tx * TN] = o;
    }
}

// ---------------------------------------------------------------------------
// Update: xk = sum of 2 K-split partials; softshrink; u update; conv check;
// write next-iteration Aeff split. One block per row, conv decision inline.
// ---------------------------------------------------------------------------
__global__ __launch_bounds__(256)
void update_kernel(const float* __restrict__ xkp, const float* __restrict__ Ab,
                   float* __restrict__ v, float* __restrict__ u,
                   float* __restrict__ enc, _Float16* __restrict__ Ah,
                   _Float16* __restrict__ Al, int* __restrict__ solved) {
    const int row = blockIdx.x;
    if (solved[row]) return;
    const int t = threadIdx.x;
    constexpr size_t P = (size_t)BATCH * OUT_F;

    float vn_all[8];
    float dx2 = 0.f, xn2 = 0.f;
#pragma unroll
    for (int g = 0; g < 2; ++g) {
        const int c = g * 1024 + t * 4;
        const size_t off = (size_t)row * OUT_F + c;
        const float4 p0 = *(const float4*)&xkp[off];
        const float4 p1 = *(const float4*)&xkp[P + off];
        const float4 u4 = *(const float4*)&u[off];
        const float4 v4 = *(const float4*)&v[off];
        const float4 ab4 = *(const float4*)&Ab[off];
        float xs[4] = {p0.x + p1.x, p0.y + p1.y, p0.z + p1.z, p0.w + p1.w};
        float us[4] = {u4.x, u4.y, u4.z, u4.w};
        float vs[4] = {v4.x, v4.y, v4.z, v4.w};
        float abs_[4] = {ab4.x, ab4.y, ab4.z, ab4.w};
        float vo[4], uo[4];
        half4 h, l;
#pragma unroll
        for (int j = 0; j < 4; ++j) {
            const float z = xs[j] + us[j];
            const float az = fabsf(z) - LAMBD;
            const float vnew = az > 0.f ? copysignf(az, z) : 0.f;
            const float unew = us[j] + xs[j] - vnew;
            const float d = vnew - vs[j];
            dx2 += d * d;
            xn2 += vnew * vnew;
            vo[j] = vnew; uo[j] = unew;
            vn_all[g * 4 + j] = vnew;
            const float aeff = abs_[j] + vnew - unew;
            const _Float16 hi = (_Float16)aeff;
            h[j] = hi;
            l[j] = (_Float16)(aeff - (float)hi);
        }
        *(float4*)&v[off] = make_float4(vo[0], vo[1], vo[2], vo[3]);
        *(float4*)&u[off] = make_float4(uo[0], uo[1], uo[2], uo[3]);
        *(half4*)&Ah[off] = h;
        *(half4*)&Al[off] = l;
    }

#pragma unroll
    for (int o = 32; o > 0; o >>= 1) {
        dx2 += __shfl_down(dx2, o);
        xn2 += __shfl_down(xn2, o);
    }
    __shared__ float sdx[4], sxn[4];
    __shared__ float s_conv;
    if ((t & 63) == 0) { sdx[t >> 6] = dx2; sxn[t >> 6] = xn2; }
    __syncthreads();
    if (t == 0) {
        const float dxt = sqrtf(sdx[0] + sdx[1] + sdx[2] + sdx[3]);
        const float xnt = sqrtf(sxn[0] + sxn[1] + sxn[2] + sxn[3]);
        const bool conv = (dxt / xnt) < TOL;   // NaN -> false, matches jnp
        s_conv = conv ? 1.f : 0.f;
        if (conv) solved[row] = 1;
    }
    __syncthreads();
    if (s_conv != 0.f) {
#pragma unroll
        for (int g = 0; g < 2; ++g) {
            const int c = g * 1024 + t * 4;
            *(float4*)&enc[(size_t)row * OUT_F + c] =
                make_float4(vn_all[g * 4], vn_all[g * 4 + 1], vn_all[g * 4 + 2], vn_all[g * 4 + 3]);
        }
    }
}

// ---------------------------------------------------------------------------
extern "C" void kernel_launch(void* const* d_in, const int* in_sizes, int n_in,
                              void* d_out, int out_size, void* d_ws, size_t ws_size,
                              hipStream_t stream) {
    (void)in_sizes; (void)n_in; (void)out_size; (void)ws_size;
    const float* x    = (const float*)d_in[0];   // 1024 x 1024
    const float* w    = (const float*)d_in[1];   // 2048 x 1024
    const float* Minv = (const float*)d_in[2];   // 2048 x 2048

    float* enc = (float*)d_out;                  // 1024 x 2048
    float* dec = enc + (size_t)BATCH * OUT_F;    // 1024 x 1024

    constexpr size_t P = (size_t)BATCH * OUT_F;  // 2M elements
    float* Ab  = (float*)d_ws;                   // 2M f32
    float* v   = Ab + P;
    float* u   = v + P;
    float* xkp = u + P;                          // 2 x 2M f32
    _Float16* Ah  = (_Float16*)(xkp + 2 * P);    // 2M f16
    _Float16* Al  = Ah + P;
    _Float16* BhT = Al + P;                      // 4M f16
    _Float16* BlT = BhT + (size_t)OUT_F * OUT_F;
    int* solved = (int*)(BlT + (size_t)OUT_F * OUT_F);

    {
        const int n4 = BATCH * OUT_F / 4;
        init_kernel<<<(n4 + 255) / 256, 256, 0, stream>>>(
            (float4*)v, (float4*)u, (float4*)enc, solved);
    }

    split_b_kernel<<<dim3(OUT_F / 32, OUT_F / 32), 256, 0, stream>>>(Minv, BhT, BlT);

    gemm_nt<<<dim3(OUT_F / BN, BATCH / BM), 256, 0, stream>>>(x, w, Ab, Ah, Al,
                                                              BATCH, OUT_F, IN_F);

    for (int it = 0; it < MAX_ITERS; ++it) {
        xk_mfma<<<dim3(OUT_F / 128, BATCH / 128, KSPLIT), 256, 0, stream>>>(
            Ah, Al, BhT, BlT, xkp, solved);
        update_kernel<<<BATCH, 256, 0, stream>>>(xkp, Ab, v, u, enc, Ah, Al, solved);
    }

    gemm_nn<<<dim3(IN_F / BN, BATCH / BM), 256, 0, stream>>>(enc, w, dec, BATCH, IN_F, OUT_F);
}

// Round 5
// 3573.059 us; speedup vs baseline: 3.3289x; 1.7938x over previous
//
#include <hip/hip_runtime.h>
#include <math.h>

#define BATCH 1024
#define IN_F  1024
#define OUT_F 2048
#define LAMBD 0.2f
#define TOL   1e-4f
#define MAX_ITERS 100

#define KSPLIT 4
#define KCHUNK (OUT_F / KSPLIT)   // 512

typedef _Float16 half8 __attribute__((ext_vector_type(8)));
typedef _Float16 half4 __attribute__((ext_vector_type(4)));
typedef float    floatx16 __attribute__((ext_vector_type(16)));

#define GLOAD_LDS16(g, l) __builtin_amdgcn_global_load_lds(              \
    (const __attribute__((address_space(1))) void*)(g),                  \
    (__attribute__((address_space(3))) void*)(l), 16, 0, 0)

// fp32 fallback GEMM tiling (one-shot GEMMs)
#define BM 64
#define BN 64
#define BK 16
#define TM 4
#define TN 4
#define LDA (BM + 4)
#define LDB (BN + 4)

// ---------------------------------------------------------------------------
__global__ void init_kernel(float4* __restrict__ v, float4* __restrict__ u,
                            float4* __restrict__ enc, int* __restrict__ solved) {
    const int i = blockIdx.x * blockDim.x + threadIdx.x;
    const int n4 = BATCH * OUT_F / 4;
    const float4 z = make_float4(0.f, 0.f, 0.f, 0.f);
    if (i < n4) { v[i] = z; u[i] = z; enc[i] = z; }
    if (i < BATCH) solved[i] = 0;
}

// ---------------------------------------------------------------------------
// Transpose + fp16-cast M_inv (2048x2048 fp32 [k][n]) -> BhT fp16 [n][k].
// ---------------------------------------------------------------------------
__global__ __launch_bounds__(256)
void split_b_kernel(const float* __restrict__ B, _Float16* __restrict__ BhT) {
    __shared__ float tile[32][33];
    const int tid = threadIdx.x;
    const int k0 = blockIdx.y * 32;
    const int n0 = blockIdx.x * 32;
    const int r = tid >> 3;
    const int c4 = (tid & 7) * 4;
    const float4 b4 = *(const float4*)&B[(size_t)(k0 + r) * OUT_F + n0 + c4];
    tile[r][c4 + 0] = b4.x; tile[r][c4 + 1] = b4.y;
    tile[r][c4 + 2] = b4.z; tile[r][c4 + 3] = b4.w;
    __syncthreads();
    half4 h;
#pragma unroll
    for (int j = 0; j < 4; ++j) h[j] = (_Float16)tile[c4 + j][r];
    *(half4*)&BhT[(size_t)(n0 + r) * OUT_F + k0 + c4] = h;
}

// ---------------------------------------------------------------------------
// NT GEMM fp32: Ab = x @ w^T, epilogue writes initial Aeff fp16 (v=u=0).
// ---------------------------------------------------------------------------
__global__ __launch_bounds__(256)
void gemm_nt(const float* __restrict__ A, const float* __restrict__ B,
             float* __restrict__ C, _Float16* __restrict__ Ah,
             int M, int N, int K) {
    __shared__ float As[BK][LDA];
    __shared__ float Bs[BK][LDB];
    const int tid = threadIdx.x;
    const int tx = tid & 15, ty = tid >> 4;
    const int m0 = blockIdx.y * BM;
    const int n0 = blockIdx.x * BN;
    const int lr = tid >> 2;
    const int lk = (tid & 3) * 4;

    float acc[TM][TN] = {};

    for (int k0 = 0; k0 < K; k0 += BK) {
        const float4 a4 = *(const float4*)&A[(size_t)(m0 + lr) * K + k0 + lk];
        const float4 b4 = *(const float4*)&B[(size_t)(n0 + lr) * K + k0 + lk];
        __syncthreads();
        As[lk + 0][lr] = a4.x; As[lk + 1][lr] = a4.y; As[lk + 2][lr] = a4.z; As[lk + 3][lr] = a4.w;
        Bs[lk + 0][lr] = b4.x; Bs[lk + 1][lr] = b4.y; Bs[lk + 2][lr] = b4.z; Bs[lk + 3][lr] = b4.w;
        __syncthreads();
#pragma unroll
        for (int kk = 0; kk < BK; ++kk) {
            const float4 av = *(const float4*)&As[kk][ty * TM];
            const float4 bv = *(const float4*)&Bs[kk][tx * TN];
            const float ar[4] = {av.x, av.y, av.z, av.w};
            const float br[4] = {bv.x, bv.y, bv.z, bv.w};
#pragma unroll
            for (int i = 0; i < TM; ++i)
#pragma unroll
                for (int j = 0; j < TN; ++j)
                    acc[i][j] = fmaf(ar[i], br[j], acc[i][j]);
        }
    }
#pragma unroll
    for (int i = 0; i < TM; ++i) {
        const size_t o = (size_t)(m0 + ty * TM + i) * N + n0 + tx * TN;
        *(float4*)&C[o] = make_float4(acc[i][0], acc[i][1], acc[i][2], acc[i][3]);
        half4 h;
#pragma unroll
        for (int j = 0; j < 4; ++j) h[j] = (_Float16)acc[i][j];
        *(half4*)&Ah[o] = h;
    }
}

// ---------------------------------------------------------------------------
// fp16 MFMA GEMM (single term): xk_part[kz] = Aeff[:, kz*512...] @ Minv[kz...]
// 128x128 tile, BK=32, 4 waves of 2x2 32x32x16_f16. Grid (16, 8, 4) = 512
// blocks = 2/CU (R4 lesson: keep >=2 blocks/CU for barrier overlap).
// ---------------------------------------------------------------------------
__global__ __launch_bounds__(256)
void xk_mfma(const _Float16* __restrict__ Ah, const _Float16* __restrict__ BhT,
             float* __restrict__ xkp, const int* __restrict__ solved) {
    __shared__ _Float16 sA[128 * 32];
    __shared__ _Float16 sB[128 * 32];
    const int tid = threadIdx.x;
    const int m0 = blockIdx.y * 128;
    const int n0 = blockIdx.x * 128;
    const int kz = blockIdx.z;

    __shared__ int s_active;
    if (tid == 0) s_active = 0;
    __syncthreads();
    if (tid < 128 && solved[m0 + tid] == 0) s_active = 1;   // benign race
    __syncthreads();
    if (!s_active) return;

    const int wv = tid >> 6;
    const int ln = tid & 63;
    const int half = ln >> 5;
    const int l31 = ln & 31;
    const int wm = (wv >> 1) * 64;
    const int wn = (wv & 1) * 64;

    // staging: [128 rows][32 halves]; two 16B issues per array per BK-step
    const int r0 = tid >> 2;
    const int koff = (tid & 3) * 8;
    const size_t ga0 = (size_t)(m0 + r0) * OUT_F + kz * KCHUNK + koff;
    const size_t ga1 = (size_t)(m0 + r0 + 64) * OUT_F + kz * KCHUNK + koff;
    const size_t gb0 = (size_t)(n0 + r0) * OUT_F + kz * KCHUNK + koff;
    const size_t gb1 = (size_t)(n0 + r0 + 64) * OUT_F + kz * KCHUNK + koff;
    const int ldst0 = tid * 8;
    const int ldst1 = (256 + tid) * 8;

    floatx16 acc[2][2];
#pragma unroll
    for (int a = 0; a < 2; ++a)
#pragma unroll
        for (int b = 0; b < 2; ++b)
#pragma unroll
            for (int r = 0; r < 16; ++r) acc[a][b][r] = 0.f;

    for (int k = 0; k < KCHUNK; k += 32) {
        __syncthreads();
        GLOAD_LDS16(Ah  + ga0 + k, sA + ldst0);
        GLOAD_LDS16(Ah  + ga1 + k, sA + ldst1);
        GLOAD_LDS16(BhT + gb0 + k, sB + ldst0);
        GLOAD_LDS16(BhT + gb1 + k, sB + ldst1);
        __syncthreads();

#pragma unroll
        for (int kk = 0; kk < 2; ++kk) {
            const int ko = kk * 16 + half * 8;
            const half8 a0 = *(const half8*)&sA[(wm + l31) * 32 + ko];
            const half8 a1 = *(const half8*)&sA[(wm + 32 + l31) * 32 + ko];
            const half8 b0 = *(const half8*)&sB[(wn + l31) * 32 + ko];
            const half8 b1 = *(const half8*)&sB[(wn + 32 + l31) * 32 + ko];

            acc[0][0] = __builtin_amdgcn_mfma_f32_32x32x16_f16(a0, b0, acc[0][0], 0, 0, 0);
            acc[0][1] = __builtin_amdgcn_mfma_f32_32x32x16_f16(a0, b1, acc[0][1], 0, 0, 0);
            acc[1][0] = __builtin_amdgcn_mfma_f32_32x32x16_f16(a1, b0, acc[1][0], 0, 0, 0);
            acc[1][1] = __builtin_amdgcn_mfma_f32_32x32x16_f16(a1, b1, acc[1][1], 0, 0, 0);
        }
    }

    float* out = xkp + (size_t)kz * BATCH * OUT_F;
#pragma unroll
    for (int mm = 0; mm < 2; ++mm)
#pragma unroll
        for (int nn = 0; nn < 2; ++nn) {
            const int col = n0 + wn + nn * 32 + l31;
#pragma unroll
            for (int r = 0; r < 16; ++r) {
                const int row = m0 + wm + mm * 32 + (r & 3) + 8 * (r >> 2) + 4 * half;
                out[(size_t)row * OUT_F + col] = acc[mm][nn][r];
            }
        }
}

// ---------------------------------------------------------------------------
// Plain NN GEMM fp32: decoded = encoded @ w  (one-shot)
// ---------------------------------------------------------------------------
__global__ __launch_bounds__(256)
void gemm_nn(const float* __restrict__ A, const float* __restrict__ B,
             float* __restrict__ C, int M, int N, int K) {
    __shared__ float As[BK][LDA];
    __shared__ float Bs[BK][LDB];
    const int tid = threadIdx.x;
    const int tx = tid & 15, ty = tid >> 4;
    const int m0 = blockIdx.y * BM;
    const int n0 = blockIdx.x * BN;
    const int lr = tid >> 2;
    const int lk = (tid & 3) * 4;
    const int kb = tid >> 4;
    const int nb = (tid & 15) * 4;

    float acc[TM][TN] = {};

    for (int k0 = 0; k0 < K; k0 += BK) {
        const float4 a4 = *(const float4*)&A[(size_t)(m0 + lr) * K + k0 + lk];
        const float4 b4 = *(const float4*)&B[(size_t)(k0 + kb) * N + n0 + nb];
        __syncthreads();
        As[lk + 0][lr] = a4.x; As[lk + 1][lr] = a4.y; As[lk + 2][lr] = a4.z; As[lk + 3][lr] = a4.w;
        *(float4*)&Bs[kb][nb] = b4;
        __syncthreads();
#pragma unroll
        for (int kk = 0; kk < BK; ++kk) {
            const float4 av = *(const float4*)&As[kk][ty * TM];
            const float4 bv = *(const float4*)&Bs[kk][tx * TN];
            const float ar[4] = {av.x, av.y, av.z, av.w};
            const float br[4] = {bv.x, bv.y, bv.z, bv.w};
#pragma unroll
            for (int i = 0; i < TM; ++i)
#pragma unroll
                for (int j = 0; j < TN; ++j)
                    acc[i][j] = fmaf(ar[i], br[j], acc[i][j]);
        }
    }
#pragma unroll
    for (int i = 0; i < TM; ++i) {
        float4 o = make_float4(acc[i][0], acc[i][1], acc[i][2], acc[i][3]);
        *(float4*)&C[(size_t)(m0 + ty * TM + i) * N + n0 + tx * TN] = o;
    }
}

// ---------------------------------------------------------------------------
// Update: xk = sum of 4 K-split partials; softshrink; u update; conv check;
// write next-iteration Aeff fp16. One block per row.
// ---------------------------------------------------------------------------
__global__ __launch_bounds__(256)
void update_kernel(const float* __restrict__ xkp, const float* __restrict__ Ab,
                   float* __restrict__ v, float* __restrict__ u,
                   float* __restrict__ enc, _Float16* __restrict__ Ah,
                   int* __restrict__ solved) {
    const int row = blockIdx.x;
    if (solved[row]) return;
    const int t = threadIdx.x;
    constexpr size_t P = (size_t)BATCH * OUT_F;

    float vn_all[8];
    float dx2 = 0.f, xn2 = 0.f;
#pragma unroll
    for (int g = 0; g < 2; ++g) {
        const int c = g * 1024 + t * 4;
        const size_t off = (size_t)row * OUT_F + c;
        const float4 p0 = *(const float4*)&xkp[off];
        const float4 p1 = *(const float4*)&xkp[P + off];
        const float4 p2 = *(const float4*)&xkp[2 * P + off];
        const float4 p3 = *(const float4*)&xkp[3 * P + off];
        const float4 u4 = *(const float4*)&u[off];
        const float4 v4 = *(const float4*)&v[off];
        const float4 ab4 = *(const float4*)&Ab[off];
        float xs[4] = {p0.x + p1.x + p2.x + p3.x, p0.y + p1.y + p2.y + p3.y,
                       p0.z + p1.z + p2.z + p3.z, p0.w + p1.w + p2.w + p3.w};
        float us[4] = {u4.x, u4.y, u4.z, u4.w};
        float vs[4] = {v4.x, v4.y, v4.z, v4.w};
        float abs_[4] = {ab4.x, ab4.y, ab4.z, ab4.w};
        float vo[4], uo[4];
        half4 h;
#pragma unroll
        for (int j = 0; j < 4; ++j) {
            const float z = xs[j] + us[j];
            const float az = fabsf(z) - LAMBD;
            const float vnew = az > 0.f ? copysignf(az, z) : 0.f;
            const float unew = us[j] + xs[j] - vnew;
            const float d = vnew - vs[j];
            dx2 += d * d;
            xn2 += vnew * vnew;
            vo[j] = vnew; uo[j] = unew;
            vn_all[g * 4 + j] = vnew;
            h[j] = (_Float16)(abs_[j] + vnew - unew);
        }
        *(float4*)&v[off] = make_float4(vo[0], vo[1], vo[2], vo[3]);
        *(float4*)&u[off] = make_float4(uo[0], uo[1], uo[2], uo[3]);
        *(half4*)&Ah[off] = h;
    }

#pragma unroll
    for (int o = 32; o > 0; o >>= 1) {
        dx2 += __shfl_down(dx2, o);
        xn2 += __shfl_down(xn2, o);
    }
    __shared__ float sdx[4], sxn[4];
    __shared__ float s_conv;
    if ((t & 63) == 0) { sdx[t >> 6] = dx2; sxn[t >> 6] = xn2; }
    __syncthreads();
    if (t == 0) {
        const float dxt = sqrtf(sdx[0] + sdx[1] + sdx[2] + sdx[3]);
        const float xnt = sqrtf(sxn[0] + sxn[1] + sxn[2] + sxn[3]);
        const bool conv = (dxt / xnt) < TOL;   // NaN -> false, matches jnp
        s_conv = conv ? 1.f : 0.f;
        if (conv) solved[row] = 1;
    }
    __syncthreads();
    if (s_conv != 0.f) {
#pragma unroll
        for (int g = 0; g < 2; ++g) {
            const int c = g * 1024 + t * 4;
            *(float4*)&enc[(size_t)row * OUT_F + c] =
                make_float4(vn_all[g * 4], vn_all[g * 4 + 1], vn_all[g * 4 + 2], vn_all[g * 4 + 3]);
        }
    }
}

// ---------------------------------------------------------------------------
extern "C" void kernel_launch(void* const* d_in, const int* in_sizes, int n_in,
                              void* d_out, int out_size, void* d_ws, size_t ws_size,
                              hipStream_t stream) {
    (void)in_sizes; (void)n_in; (void)out_size; (void)ws_size;
    const float* x    = (const float*)d_in[0];   // 1024 x 1024
    const float* w    = (const float*)d_in[1];   // 2048 x 1024
    const float* Minv = (const float*)d_in[2];   // 2048 x 2048

    float* enc = (float*)d_out;                  // 1024 x 2048
    float* dec = enc + (size_t)BATCH * OUT_F;    // 1024 x 1024

    constexpr size_t P = (size_t)BATCH * OUT_F;  // 2M elements
    float* Ab  = (float*)d_ws;                   // 2M f32
    float* v   = Ab + P;
    float* u   = v + P;
    float* xkp = u + P;                          // 4 x 2M f32
    _Float16* Ah  = (_Float16*)(xkp + 4 * P);    // 2M f16
    _Float16* BhT = Ah + P;                      // 4M f16
    int* solved = (int*)(BhT + (size_t)OUT_F * OUT_F);

    {
        const int n4 = BATCH * OUT_F / 4;
        init_kernel<<<(n4 + 255) / 256, 256, 0, stream>>>(
            (float4*)v, (float4*)u, (float4*)enc, solved);
    }

    split_b_kernel<<<dim3(OUT_F / 32, OUT_F / 32), 256, 0, stream>>>(Minv, BhT);

    gemm_nt<<<dim3(OUT_F / BN, BATCH / BM), 256, 0, stream>>>(x, w, Ab, Ah,
                                                              BATCH, OUT_F, IN_F);

    for (int it = 0; it < MAX_ITERS; ++it) {
        xk_mfma<<<dim3(OUT_F / 128, BATCH / 128, KSPLIT), 256, 0, stream>>>(
            Ah, BhT, xkp, solved);
        update_kernel<<<BATCH, 256, 0, stream>>>(xkp, Ab, v, u, enc, Ah, solved);
    }

    gemm_nn<<<dim3(IN_F / BN, BATCH / BM), 256, 0, stream>>>(enc, w, dec, BATCH, IN_F, OUT_F);
}

// Round 6
// 2939.591 us; speedup vs baseline: 4.0463x; 1.2155x over previous
//
#include <hip/hip_runtime.h>
#include <math.h>

#define BATCH 1024
#define IN_F  1024
#define OUT_F 2048
#define LAMBD 0.2f
#define TOL   1e-4f
#define MAX_ITERS 100

#define KSPLIT 4
#define KCHUNK (OUT_F / KSPLIT)   // 512

typedef _Float16 half8 __attribute__((ext_vector_type(8)));
typedef _Float16 half4 __attribute__((ext_vector_type(4)));
typedef float    floatx16 __attribute__((ext_vector_type(16)));

#define GLOAD_LDS16(g, l) __builtin_amdgcn_global_load_lds(              \
    (const __attribute__((address_space(1))) void*)(g),                  \
    (__attribute__((address_space(3))) void*)(l), 16, 0, 0)

// fp32 fallback GEMM tiling (one-shot GEMMs)
#define BM 64
#define BN 64
#define BK 16
#define TM 4
#define TN 4
#define LDA (BM + 4)
#define LDB (BN + 4)

// ---------------------------------------------------------------------------
// init: zero v,u (fp16), enc (fp32 out), solved flags
// ---------------------------------------------------------------------------
__global__ void init_kernel(float4* __restrict__ v16, float4* __restrict__ u16,
                            float4* __restrict__ enc, int* __restrict__ solved) {
    const int i = blockIdx.x * blockDim.x + threadIdx.x;
    const float4 z = make_float4(0.f, 0.f, 0.f, 0.f);
    const int nh = BATCH * OUT_F / 8;    // v,u as 16B chunks (8 halves)
    const int n4 = BATCH * OUT_F / 4;    // enc as 16B chunks (4 floats)
    if (i < nh) { v16[i] = z; u16[i] = z; }
    if (i < n4) enc[i] = z;
    if (i < BATCH) solved[i] = 0;
}

// ---------------------------------------------------------------------------
// Transpose + fp16-cast M_inv (2048x2048 fp32 [k][n]) -> BhT fp16 [n][k].
// ---------------------------------------------------------------------------
__global__ __launch_bounds__(256)
void split_b_kernel(const float* __restrict__ B, _Float16* __restrict__ BhT) {
    __shared__ float tile[32][33];
    const int tid = threadIdx.x;
    const int k0 = blockIdx.y * 32;
    const int n0 = blockIdx.x * 32;
    const int r = tid >> 3;
    const int c4 = (tid & 7) * 4;
    const float4 b4 = *(const float4*)&B[(size_t)(k0 + r) * OUT_F + n0 + c4];
    tile[r][c4 + 0] = b4.x; tile[r][c4 + 1] = b4.y;
    tile[r][c4 + 2] = b4.z; tile[r][c4 + 3] = b4.w;
    __syncthreads();
    half4 h;
#pragma unroll
    for (int j = 0; j < 4; ++j) h[j] = (_Float16)tile[c4 + j][r];
    *(half4*)&BhT[(size_t)(n0 + r) * OUT_F + k0 + c4] = h;
}

// ---------------------------------------------------------------------------
// NT GEMM fp32: Ab = x @ w^T -> fp16 Abh (persistent) + initial Aeff (= Abh).
// ---------------------------------------------------------------------------
__global__ __launch_bounds__(256)
void gemm_nt(const float* __restrict__ A, const float* __restrict__ B,
             _Float16* __restrict__ Abh, _Float16* __restrict__ Ah,
             int M, int N, int K) {
    __shared__ float As[BK][LDA];
    __shared__ float Bs[BK][LDB];
    const int tid = threadIdx.x;
    const int tx = tid & 15, ty = tid >> 4;
    const int m0 = blockIdx.y * BM;
    const int n0 = blockIdx.x * BN;
    const int lr = tid >> 2;
    const int lk = (tid & 3) * 4;

    float acc[TM][TN] = {};

    for (int k0 = 0; k0 < K; k0 += BK) {
        const float4 a4 = *(const float4*)&A[(size_t)(m0 + lr) * K + k0 + lk];
        const float4 b4 = *(const float4*)&B[(size_t)(n0 + lr) * K + k0 + lk];
        __syncthreads();
        As[lk + 0][lr] = a4.x; As[lk + 1][lr] = a4.y; As[lk + 2][lr] = a4.z; As[lk + 3][lr] = a4.w;
        Bs[lk + 0][lr] = b4.x; Bs[lk + 1][lr] = b4.y; Bs[lk + 2][lr] = b4.z; Bs[lk + 3][lr] = b4.w;
        __syncthreads();
#pragma unroll
        for (int kk = 0; kk < BK; ++kk) {
            const float4 av = *(const float4*)&As[kk][ty * TM];
            const float4 bv = *(const float4*)&Bs[kk][tx * TN];
            const float ar[4] = {av.x, av.y, av.z, av.w};
            const float br[4] = {bv.x, bv.y, bv.z, bv.w};
#pragma unroll
            for (int i = 0; i < TM; ++i)
#pragma unroll
                for (int j = 0; j < TN; ++j)
                    acc[i][j] = fmaf(ar[i], br[j], acc[i][j]);
        }
    }
#pragma unroll
    for (int i = 0; i < TM; ++i) {
        const size_t o = (size_t)(m0 + ty * TM + i) * N + n0 + tx * TN;
        half4 h;
#pragma unroll
        for (int j = 0; j < 4; ++j) h[j] = (_Float16)acc[i][j];
        *(half4*)&Abh[o] = h;
        *(half4*)&Ah[o] = h;     // initial Aeff (v=u=0)
    }
}

// ---------------------------------------------------------------------------
// fp16 MFMA GEMM: xk_part[kz] = Aeff[:, kz*512...] @ Minv[kz...], fp16 out.
// 128x128 tile, BK=32, 4 waves of 2x2 32x32x16_f16. Grid (16,8,4) = 512
// blocks = 2/CU (R4 lesson: keep >=2 blocks/CU for barrier overlap).
// ---------------------------------------------------------------------------
__global__ __launch_bounds__(256)
void xk_mfma(const _Float16* __restrict__ Ah, const _Float16* __restrict__ BhT,
             _Float16* __restrict__ xkp, const int* __restrict__ solved) {
    __shared__ _Float16 sA[128 * 32];
    __shared__ _Float16 sB[128 * 32];
    const int tid = threadIdx.x;
    const int m0 = blockIdx.y * 128;
    const int n0 = blockIdx.x * 128;
    const int kz = blockIdx.z;

    __shared__ int s_active;
    if (tid == 0) s_active = 0;
    __syncthreads();
    if (tid < 128 && solved[m0 + tid] == 0) s_active = 1;   // benign race
    __syncthreads();
    if (!s_active) return;

    const int wv = tid >> 6;
    const int ln = tid & 63;
    const int half = ln >> 5;
    const int l31 = ln & 31;
    const int wm = (wv >> 1) * 64;
    const int wn = (wv & 1) * 64;

    const int r0 = tid >> 2;
    const int koff = (tid & 3) * 8;
    const size_t ga0 = (size_t)(m0 + r0) * OUT_F + kz * KCHUNK + koff;
    const size_t ga1 = (size_t)(m0 + r0 + 64) * OUT_F + kz * KCHUNK + koff;
    const size_t gb0 = (size_t)(n0 + r0) * OUT_F + kz * KCHUNK + koff;
    const size_t gb1 = (size_t)(n0 + r0 + 64) * OUT_F + kz * KCHUNK + koff;
    const int ldst0 = tid * 8;
    const int ldst1 = (256 + tid) * 8;

    floatx16 acc[2][2];
#pragma unroll
    for (int a = 0; a < 2; ++a)
#pragma unroll
        for (int b = 0; b < 2; ++b)
#pragma unroll
            for (int r = 0; r < 16; ++r) acc[a][b][r] = 0.f;

    for (int k = 0; k < KCHUNK; k += 32) {
        __syncthreads();
        GLOAD_LDS16(Ah  + ga0 + k, sA + ldst0);
        GLOAD_LDS16(Ah  + ga1 + k, sA + ldst1);
        GLOAD_LDS16(BhT + gb0 + k, sB + ldst0);
        GLOAD_LDS16(BhT + gb1 + k, sB + ldst1);
        __syncthreads();

#pragma unroll
        for (int kk = 0; kk < 2; ++kk) {
            const int ko = kk * 16 + half * 8;
            const half8 a0 = *(const half8*)&sA[(wm + l31) * 32 + ko];
            const half8 a1 = *(const half8*)&sA[(wm + 32 + l31) * 32 + ko];
            const half8 b0 = *(const half8*)&sB[(wn + l31) * 32 + ko];
            const half8 b1 = *(const half8*)&sB[(wn + 32 + l31) * 32 + ko];

            acc[0][0] = __builtin_amdgcn_mfma_f32_32x32x16_f16(a0, b0, acc[0][0], 0, 0, 0);
            acc[0][1] = __builtin_amdgcn_mfma_f32_32x32x16_f16(a0, b1, acc[0][1], 0, 0, 0);
            acc[1][0] = __builtin_amdgcn_mfma_f32_32x32x16_f16(a1, b0, acc[1][0], 0, 0, 0);
            acc[1][1] = __builtin_amdgcn_mfma_f32_32x32x16_f16(a1, b1, acc[1][1], 0, 0, 0);
        }
    }

    _Float16* out = xkp + (size_t)kz * BATCH * OUT_F;
#pragma unroll
    for (int mm = 0; mm < 2; ++mm)
#pragma unroll
        for (int nn = 0; nn < 2; ++nn) {
            const int col = n0 + wn + nn * 32 + l31;
#pragma unroll
            for (int r = 0; r < 16; ++r) {
                const int row = m0 + wm + mm * 32 + (r & 3) + 8 * (r >> 2) + 4 * half;
                out[(size_t)row * OUT_F + col] = (_Float16)acc[mm][nn][r];
            }
        }
}

// ---------------------------------------------------------------------------
// Plain NN GEMM fp32: decoded = encoded @ w  (one-shot)
// ---------------------------------------------------------------------------
__global__ __launch_bounds__(256)
void gemm_nn(const float* __restrict__ A, const float* __restrict__ B,
             float* __restrict__ C, int M, int N, int K) {
    __shared__ float As[BK][LDA];
    __shared__ float Bs[BK][LDB];
    const int tid = threadIdx.x;
    const int tx = tid & 15, ty = tid >> 4;
    const int m0 = blockIdx.y * BM;
    const int n0 = blockIdx.x * BN;
    const int lr = tid >> 2;
    const int lk = (tid & 3) * 4;
    const int kb = tid >> 4;
    const int nb = (tid & 15) * 4;

    float acc[TM][TN] = {};

    for (int k0 = 0; k0 < K; k0 += BK) {
        const float4 a4 = *(const float4*)&A[(size_t)(m0 + lr) * K + k0 + lk];
        const float4 b4 = *(const float4*)&B[(size_t)(k0 + kb) * N + n0 + nb];
        __syncthreads();
        As[lk + 0][lr] = a4.x; As[lk + 1][lr] = a4.y; As[lk + 2][lr] = a4.z; As[lk + 3][lr] = a4.w;
        *(float4*)&Bs[kb][nb] = b4;
        __syncthreads();
#pragma unroll
        for (int kk = 0; kk < BK; ++kk) {
            const float4 av = *(const float4*)&As[kk][ty * TM];
            const float4 bv = *(const float4*)&Bs[kk][tx * TN];
            const float ar[4] = {av.x, av.y, av.z, av.w};
            const float br[4] = {bv.x, bv.y, bv.z, bv.w};
#pragma unroll
            for (int i = 0; i < TM; ++i)
#pragma unroll
                for (int j = 0; j < TN; ++j)
                    acc[i][j] = fmaf(ar[i], br[j], acc[i][j]);
        }
    }
#pragma unroll
    for (int i = 0; i < TM; ++i) {
        float4 o = make_float4(acc[i][0], acc[i][1], acc[i][2], acc[i][3]);
        *(float4*)&C[(size_t)(m0 + ty * TM + i) * N + n0 + tx * TN] = o;
    }
}

// ---------------------------------------------------------------------------
// Update: xk = sum of 4 fp16 partials; softshrink; u update; conv check;
// write next Aeff fp16. One block per row; one half8 (16B) per thread/array.
// ---------------------------------------------------------------------------
__global__ __launch_bounds__(256)
void update_kernel(const _Float16* __restrict__ xkp, const _Float16* __restrict__ Abh,
                   _Float16* __restrict__ v, _Float16* __restrict__ u,
                   float* __restrict__ enc, _Float16* __restrict__ Ah,
                   int* __restrict__ solved) {
    const int row = blockIdx.x;
    if (solved[row]) return;
    const int t = threadIdx.x;
    constexpr size_t P = (size_t)BATCH * OUT_F;

    const int c = t * 8;                      // 256 threads x 8 = 2048 cols
    const size_t off = (size_t)row * OUT_F + c;
    const half8 p0 = *(const half8*)&xkp[off];
    const half8 p1 = *(const half8*)&xkp[P + off];
    const half8 p2 = *(const half8*)&xkp[2 * P + off];
    const half8 p3 = *(const half8*)&xkp[3 * P + off];
    const half8 u8 = *(const half8*)&u[off];
    const half8 v8 = *(const half8*)&v[off];
    const half8 ab8 = *(const half8*)&Abh[off];

    float vn_all[8];
    half8 vo, uo, ho;
    float dx2 = 0.f, xn2 = 0.f;
#pragma unroll
    for (int j = 0; j < 8; ++j) {
        const float xk = (float)p0[j] + (float)p1[j] + (float)p2[j] + (float)p3[j];
        const float uv = (float)u8[j];
        const float vp = (float)v8[j];
        const float z = xk + uv;
        const float az = fabsf(z) - LAMBD;
        const float vnew = az > 0.f ? copysignf(az, z) : 0.f;
        const float unew = uv + xk - vnew;
        const float d = vnew - vp;
        dx2 += d * d;
        xn2 += vnew * vnew;
        vn_all[j] = vnew;
        vo[j] = (_Float16)vnew;
        uo[j] = (_Float16)unew;
        ho[j] = (_Float16)((float)ab8[j] + vnew - unew);
    }
    *(half8*)&v[off] = vo;
    *(half8*)&u[off] = uo;
    *(half8*)&Ah[off] = ho;

#pragma unroll
    for (int o = 32; o > 0; o >>= 1) {
        dx2 += __shfl_down(dx2, o);
        xn2 += __shfl_down(xn2, o);
    }
    __shared__ float sdx[4], sxn[4];
    __shared__ float s_conv;
    if ((t & 63) == 0) { sdx[t >> 6] = dx2; sxn[t >> 6] = xn2; }
    __syncthreads();
    if (t == 0) {
        const float dxt = sqrtf(sdx[0] + sdx[1] + sdx[2] + sdx[3]);
        const float xnt = sqrtf(sxn[0] + sxn[1] + sxn[2] + sxn[3]);
        const bool conv = (dxt / xnt) < TOL;   // NaN -> false, matches jnp
        s_conv = conv ? 1.f : 0.f;
        if (conv) solved[row] = 1;
    }
    __syncthreads();
    if (s_conv != 0.f) {
        *(float4*)&enc[off] = make_float4(vn_all[0], vn_all[1], vn_all[2], vn_all[3]);
        *(float4*)&enc[off + 4] = make_float4(vn_all[4], vn_all[5], vn_all[6], vn_all[7]);
    }
}

// ---------------------------------------------------------------------------
extern "C" void kernel_launch(void* const* d_in, const int* in_sizes, int n_in,
                              void* d_out, int out_size, void* d_ws, size_t ws_size,
                              hipStream_t stream) {
    (void)in_sizes; (void)n_in; (void)out_size; (void)ws_size;
    const float* x    = (const float*)d_in[0];   // 1024 x 1024
    const float* w    = (const float*)d_in[1];   // 2048 x 1024
    const float* Minv = (const float*)d_in[2];   // 2048 x 2048

    float* enc = (float*)d_out;                  // 1024 x 2048
    float* dec = enc + (size_t)BATCH * OUT_F;    // 1024 x 1024

    constexpr size_t P = (size_t)BATCH * OUT_F;  // 2M elements
    _Float16* Abh = (_Float16*)d_ws;             // P f16
    _Float16* v   = Abh + P;                     // P f16
    _Float16* u   = v + P;                       // P f16
    _Float16* Ah  = u + P;                       // P f16
    _Float16* xkp = Ah + P;                      // 4P f16
    _Float16* BhT = xkp + 4 * P;                 // 4M f16
    int* solved = (int*)(BhT + (size_t)OUT_F * OUT_F);

    {
        const int n = BATCH * OUT_F / 4;   // covers enc; v/u need half as many
        init_kernel<<<(n + 255) / 256, 256, 0, stream>>>(
            (float4*)v, (float4*)u, (float4*)enc, solved);
    }

    split_b_kernel<<<dim3(OUT_F / 32, OUT_F / 32), 256, 0, stream>>>(Minv, BhT);

    gemm_nt<<<dim3(OUT_F / BN, BATCH / BM), 256, 0, stream>>>(x, w, Abh, Ah,
                                                              BATCH, OUT_F, IN_F);

    for (int it = 0; it < MAX_ITERS; ++it) {
        xk_mfma<<<dim3(OUT_F / 128, BATCH / 128, KSPLIT), 256, 0, stream>>>(
            Ah, BhT, xkp, solved);
        update_kernel<<<BATCH, 256, 0, stream>>>(xkp, Abh, v, u, enc, Ah, solved);
    }

    gemm_nn<<<dim3(IN_F / BN, BATCH / BM), 256, 0, stream>>>(enc, w, dec, BATCH, IN_F, OUT_F);
}

// Round 8
// 2411.620 us; speedup vs baseline: 4.9321x; 1.2189x over previous
//
#include <hip/hip_runtime.h>
#include <math.h>

#define BATCH 1024
#define IN_F  1024
#define OUT_F 2048
#define LAMBD 0.2f
#define TOL   1e-4f
#define MAX_ITERS 100

#define KSPLIT 4
#define KCHUNK (OUT_F / KSPLIT)   // 512
#define BSCALE 32.0f
#define BSCALE_INV 0.03125f

typedef _Float16 half8 __attribute__((ext_vector_type(8)));
typedef _Float16 half4 __attribute__((ext_vector_type(4)));
typedef float    floatx16 __attribute__((ext_vector_type(16)));
typedef unsigned char fp8_t;

#define GLOAD_LDS16(g, l) __builtin_amdgcn_global_load_lds(              \
    (const __attribute__((address_space(1))) void*)(g),                  \
    (__attribute__((address_space(3))) void*)(l), 16, 0, 0)

// fp8 e4m3 (OCP on gfx950) HW converts
__device__ inline int pk4_fp8(float a, float b, float c, float d) {
    int w = __builtin_amdgcn_cvt_pk_fp8_f32(a, b, 0, false);
    w = __builtin_amdgcn_cvt_pk_fp8_f32(c, d, w, true);
    return w;
}
__device__ inline fp8_t enc_fp8(float a) {
    return (fp8_t)(__builtin_amdgcn_cvt_pk_fp8_f32(a, a, 0, false) & 0xff);
}
// byte-selector must be a literal constant -> expand all four
__device__ inline void cvt4_fp8(int w, float o[4]) {
    o[0] = __builtin_amdgcn_cvt_f32_fp8(w, 0);
    o[1] = __builtin_amdgcn_cvt_f32_fp8(w, 1);
    o[2] = __builtin_amdgcn_cvt_f32_fp8(w, 2);
    o[3] = __builtin_amdgcn_cvt_f32_fp8(w, 3);
}

// fp32 fallback GEMM tiling (one-shot GEMMs)
#define BM 64
#define BN 64
#define BK 16
#define TM 4
#define TN 4
#define LDA (BM + 4)
#define LDB (BN + 4)

// ---------------------------------------------------------------------------
// init: zero v,u (fp16), enc (fp32 out), solved flags
// ---------------------------------------------------------------------------
__global__ void init_kernel(float4* __restrict__ v16, float4* __restrict__ u16,
                            float4* __restrict__ enc, int* __restrict__ solved) {
    const int i = blockIdx.x * blockDim.x + threadIdx.x;
    const float4 z = make_float4(0.f, 0.f, 0.f, 0.f);
    const int nh = BATCH * OUT_F / 8;    // v,u as 16B chunks (8 halves)
    const int n4 = BATCH * OUT_F / 4;    // enc as 16B chunks (4 floats)
    if (i < nh) { v16[i] = z; u16[i] = z; }
    if (i < n4) enc[i] = z;
    if (i < BATCH) solved[i] = 0;
}

// ---------------------------------------------------------------------------
// Transpose + fp8-cast (x32) M_inv (2048x2048 fp32 [k][n]) -> BhT fp8 [n][k].
// ---------------------------------------------------------------------------
__global__ __launch_bounds__(256)
void split_b_kernel(const float* __restrict__ B, fp8_t* __restrict__ BhT) {
    __shared__ float tile[32][33];
    const int tid = threadIdx.x;
    const int k0 = blockIdx.y * 32;
    const int n0 = blockIdx.x * 32;
    const int r = tid >> 3;
    const int c4 = (tid & 7) * 4;
    const float4 b4 = *(const float4*)&B[(size_t)(k0 + r) * OUT_F + n0 + c4];
    tile[r][c4 + 0] = b4.x; tile[r][c4 + 1] = b4.y;
    tile[r][c4 + 2] = b4.z; tile[r][c4 + 3] = b4.w;
    __syncthreads();
    const int w = pk4_fp8(tile[c4 + 0][r] * BSCALE, tile[c4 + 1][r] * BSCALE,
                          tile[c4 + 2][r] * BSCALE, tile[c4 + 3][r] * BSCALE);
    *(int*)&BhT[(size_t)(n0 + r) * OUT_F + k0 + c4] = w;
}

// ---------------------------------------------------------------------------
// NT GEMM fp32: Ab = x @ w^T -> Abh fp16 (persistent) + initial Aeff fp8.
// ---------------------------------------------------------------------------
__global__ __launch_bounds__(256)
void gemm_nt(const float* __restrict__ A, const float* __restrict__ B,
             _Float16* __restrict__ Abh, fp8_t* __restrict__ Ah,
             int M, int N, int K) {
    __shared__ float As[BK][LDA];
    __shared__ float Bs[BK][LDB];
    const int tid = threadIdx.x;
    const int tx = tid & 15, ty = tid >> 4;
    const int m0 = blockIdx.y * BM;
    const int n0 = blockIdx.x * BN;
    const int lr = tid >> 2;
    const int lk = (tid & 3) * 4;

    float acc[TM][TN] = {};

    for (int k0 = 0; k0 < K; k0 += BK) {
        const float4 a4 = *(const float4*)&A[(size_t)(m0 + lr) * K + k0 + lk];
        const float4 b4 = *(const float4*)&B[(size_t)(n0 + lr) * K + k0 + lk];
        __syncthreads();
        As[lk + 0][lr] = a4.x; As[lk + 1][lr] = a4.y; As[lk + 2][lr] = a4.z; As[lk + 3][lr] = a4.w;
        Bs[lk + 0][lr] = b4.x; Bs[lk + 1][lr] = b4.y; Bs[lk + 2][lr] = b4.z; Bs[lk + 3][lr] = b4.w;
        __syncthreads();
#pragma unroll
        for (int kk = 0; kk < BK; ++kk) {
            const float4 av = *(const float4*)&As[kk][ty * TM];
            const float4 bv = *(const float4*)&Bs[kk][tx * TN];
            const float ar[4] = {av.x, av.y, av.z, av.w};
            const float br[4] = {bv.x, bv.y, bv.z, bv.w};
#pragma unroll
            for (int i = 0; i < TM; ++i)
#pragma unroll
                for (int j = 0; j < TN; ++j)
                    acc[i][j] = fmaf(ar[i], br[j], acc[i][j]);
        }
    }
#pragma unroll
    for (int i = 0; i < TM; ++i) {
        const size_t o = (size_t)(m0 + ty * TM + i) * N + n0 + tx * TN;
        half4 h;
#pragma unroll
        for (int j = 0; j < 4; ++j) h[j] = (_Float16)acc[i][j];
        *(half4*)&Abh[o] = h;
        *(int*)&Ah[o] = pk4_fp8(acc[i][0], acc[i][1], acc[i][2], acc[i][3]);
    }
}

// ---------------------------------------------------------------------------
// fp8 MFMA GEMM: xk_part[kz] = Aeff[:, kz*512...] @ (32*Minv)[kz...] / 32.
// 128x128 tile, BK=64, KSPLIT=4, grid (16,8,4)=512 blocks = 2/CU.
// LDS layout: column-major 16B chunks (slot = chunk*128 + row) staged via
// per-lane gather global_load_lds -> conflict-free b64 fragment reads.
// ---------------------------------------------------------------------------
__global__ __launch_bounds__(256)
void xk_mfma(const fp8_t* __restrict__ Ah, const fp8_t* __restrict__ BhT,
             fp8_t* __restrict__ xkp, const int* __restrict__ solved) {
    __shared__ fp8_t sA[128 * 64];   // 8KB
    __shared__ fp8_t sB[128 * 64];   // 8KB
    const int tid = threadIdx.x;
    const int m0 = blockIdx.y * 128;
    const int n0 = blockIdx.x * 128;
    const int kz = blockIdx.z;

    __shared__ int s_active;
    if (tid == 0) s_active = 0;
    __syncthreads();
    if (tid < 128 && solved[m0 + tid] == 0) s_active = 1;   // benign race
    __syncthreads();
    if (!s_active) return;

    const int wv = tid >> 6;
    const int ln = tid & 63;
    const int half = ln >> 5;
    const int l31 = ln & 31;
    const int wm = (wv >> 1) * 64;
    const int wn = (wv & 1) * 64;

    // gather staging: issue i in {0,1}: slot s = i*256+tid; chunk c = s>>7,
    // row r = s&127; global byte = row_base + k + c*16; LDS byte = s*16.
    const int r = tid & 127;
    const int c0 = tid >> 7;           // 0 or 1
    const fp8_t* gA = Ah  + (size_t)(m0 + r) * OUT_F + kz * KCHUNK;
    const fp8_t* gB = BhT + (size_t)(n0 + r) * OUT_F + kz * KCHUNK;
    fp8_t* lA0 = sA + (c0 * 128 + r) * 16;
    fp8_t* lA1 = sA + ((c0 + 2) * 128 + r) * 16;
    fp8_t* lB0 = sB + (c0 * 128 + r) * 16;
    fp8_t* lB1 = sB + ((c0 + 2) * 128 + r) * 16;

    floatx16 acc[2][2];
#pragma unroll
    for (int a = 0; a < 2; ++a)
#pragma unroll
        for (int b = 0; b < 2; ++b)
#pragma unroll
            for (int q = 0; q < 16; ++q) acc[a][b][q] = 0.f;

    // fragment LDS offsets: chunk kk covers k16 [kk*16,+16); half picks 8B
    const int ao0 = (wm + l31) * 16 + half * 8;
    const int ao1 = (wm + 32 + l31) * 16 + half * 8;
    const int bo0 = (wn + l31) * 16 + half * 8;
    const int bo1 = (wn + 32 + l31) * 16 + half * 8;

    for (int k = 0; k < KCHUNK; k += 64) {
        __syncthreads();
        GLOAD_LDS16(gA + k + c0 * 16, lA0);
        GLOAD_LDS16(gA + k + (c0 + 2) * 16, lA1);
        GLOAD_LDS16(gB + k + c0 * 16, lB0);
        GLOAD_LDS16(gB + k + (c0 + 2) * 16, lB1);
        __syncthreads();

#pragma unroll
        for (int kk = 0; kk < 4; ++kk) {
            const int cb = kk * 2048;
            const long long a0 = *(const long long*)&sA[cb + ao0];
            const long long a1 = *(const long long*)&sA[cb + ao1];
            const long long b0 = *(const long long*)&sB[cb + bo0];
            const long long b1 = *(const long long*)&sB[cb + bo1];
            acc[0][0] = __builtin_amdgcn_mfma_f32_32x32x16_fp8_fp8(a0, b0, acc[0][0], 0, 0, 0);
            acc[0][1] = __builtin_amdgcn_mfma_f32_32x32x16_fp8_fp8(a0, b1, acc[0][1], 0, 0, 0);
            acc[1][0] = __builtin_amdgcn_mfma_f32_32x32x16_fp8_fp8(a1, b0, acc[1][0], 0, 0, 0);
            acc[1][1] = __builtin_amdgcn_mfma_f32_32x32x16_fp8_fp8(a1, b1, acc[1][1], 0, 0, 0);
        }
    }

    fp8_t* out = xkp + (size_t)kz * BATCH * OUT_F;
#pragma unroll
    for (int mm = 0; mm < 2; ++mm)
#pragma unroll
        for (int nn = 0; nn < 2; ++nn) {
            const int col = n0 + wn + nn * 32 + l31;
#pragma unroll
            for (int q = 0; q < 16; ++q) {
                const int row = m0 + wm + mm * 32 + (q & 3) + 8 * (q >> 2) + 4 * half;
                out[(size_t)row * OUT_F + col] = enc_fp8(acc[mm][nn][q] * BSCALE_INV);
            }
        }
}

// ---------------------------------------------------------------------------
// Plain NN GEMM fp32: decoded = encoded @ w  (one-shot)
// ---------------------------------------------------------------------------
__global__ __launch_bounds__(256)
void gemm_nn(const float* __restrict__ A, const float* __restrict__ B,
             float* __restrict__ C, int M, int N, int K) {
    __shared__ float As[BK][LDA];
    __shared__ float Bs[BK][LDB];
    const int tid = threadIdx.x;
    const int tx = tid & 15, ty = tid >> 4;
    const int m0 = blockIdx.y * BM;
    const int n0 = blockIdx.x * BN;
    const int lr = tid >> 2;
    const int lk = (tid & 3) * 4;
    const int kb = tid >> 4;
    const int nb = (tid & 15) * 4;

    float acc[TM][TN] = {};

    for (int k0 = 0; k0 < K; k0 += BK) {
        const float4 a4 = *(const float4*)&A[(size_t)(m0 + lr) * K + k0 + lk];
        const float4 b4 = *(const float4*)&B[(size_t)(k0 + kb) * N + n0 + nb];
        __syncthreads();
        As[lk + 0][lr] = a4.x; As[lk + 1][lr] = a4.y; As[lk + 2][lr] = a4.z; As[lk + 3][lr] = a4.w;
        *(float4*)&Bs[kb][nb] = b4;
        __syncthreads();
#pragma unroll
        for (int kk = 0; kk < BK; ++kk) {
            const float4 av = *(const float4*)&As[kk][ty * TM];
            const float4 bv = *(const float4*)&Bs[kk][tx * TN];
            const float ar[4] = {av.x, av.y, av.z, av.w};
            const float br[4] = {bv.x, bv.y, bv.z, bv.w};
#pragma unroll
            for (int i = 0; i < TM; ++i)
#pragma unroll
                for (int j = 0; j < TN; ++j)
                    acc[i][j] = fmaf(ar[i], br[j], acc[i][j]);
        }
    }
#pragma unroll
    for (int i = 0; i < TM; ++i) {
        float4 o = make_float4(acc[i][0], acc[i][1], acc[i][2], acc[i][3]);
        *(float4*)&C[(size_t)(m0 + ty * TM + i) * N + n0 + tx * TN] = o;
    }
}

// ---------------------------------------------------------------------------
// Update: xk = sum of 4 fp8 partials; softshrink; u update; conv check;
// write next Aeff fp8. One block per row; 8 elements per thread.
// ---------------------------------------------------------------------------
__global__ __launch_bounds__(256)
void update_kernel(const fp8_t* __restrict__ xkp, const _Float16* __restrict__ Abh,
                   _Float16* __restrict__ v, _Float16* __restrict__ u,
                   float* __restrict__ enc, fp8_t* __restrict__ Ah,
                   int* __restrict__ solved) {
    const int row = blockIdx.x;
    if (solved[row]) return;
    const int t = threadIdx.x;
    constexpr size_t P = (size_t)BATCH * OUT_F;

    const int c = t * 8;                      // 256 threads x 8 = 2048 cols
    const size_t off = (size_t)row * OUT_F + c;
    const int2 q0 = *(const int2*)&xkp[off];
    const int2 q1 = *(const int2*)&xkp[P + off];
    const int2 q2 = *(const int2*)&xkp[2 * P + off];
    const int2 q3 = *(const int2*)&xkp[3 * P + off];
    const half8 u8 = *(const half8*)&u[off];
    const half8 v8 = *(const half8*)&v[off];
    const half8 ab8 = *(const half8*)&Abh[off];

    float f0[4], f1[4], f2[4], f3[4], g0[4], g1[4], g2[4], g3[4];
    cvt4_fp8(q0.x, f0); cvt4_fp8(q1.x, f1); cvt4_fp8(q2.x, f2); cvt4_fp8(q3.x, f3);
    cvt4_fp8(q0.y, g0); cvt4_fp8(q1.y, g1); cvt4_fp8(q2.y, g2); cvt4_fp8(q3.y, g3);
    float xs[8];
#pragma unroll
    for (int j = 0; j < 4; ++j) {
        xs[j] = f0[j] + f1[j] + f2[j] + f3[j];
        xs[j + 4] = g0[j] + g1[j] + g2[j] + g3[j];
    }

    float vn_all[8], ae[8];
    half8 vo, uo;
    float dx2 = 0.f, xn2 = 0.f;
#pragma unroll
    for (int j = 0; j < 8; ++j) {
        const float xk = xs[j];
        const float uv = (float)u8[j];
        const float vp = (float)v8[j];
        const float z = xk + uv;
        const float az = fabsf(z) - LAMBD;
        const float vnew = az > 0.f ? copysignf(az, z) : 0.f;
        const float unew = uv + xk - vnew;
        const float d = vnew - vp;
        dx2 += d * d;
        xn2 += vnew * vnew;
        vn_all[j] = vnew;
        vo[j] = (_Float16)vnew;
        uo[j] = (_Float16)unew;
        ae[j] = (float)ab8[j] + vnew - unew;
    }
    *(half8*)&v[off] = vo;
    *(half8*)&u[off] = uo;
    int2 ah;
    ah.x = pk4_fp8(ae[0], ae[1], ae[2], ae[3]);
    ah.y = pk4_fp8(ae[4], ae[5], ae[6], ae[7]);
    *(int2*)&Ah[off] = ah;

#pragma unroll
    for (int o = 32; o > 0; o >>= 1) {
        dx2 += __shfl_down(dx2, o);
        xn2 += __shfl_down(xn2, o);
    }
    __shared__ float sdx[4], sxn[4];
    __shared__ float s_conv;
    if ((t & 63) == 0) { sdx[t >> 6] = dx2; sxn[t >> 6] = xn2; }
    __syncthreads();
    if (t == 0) {
        const float dxt = sqrtf(sdx[0] + sdx[1] + sdx[2] + sdx[3]);
        const float xnt = sqrtf(sxn[0] + sxn[1] + sxn[2] + sxn[3]);
        const bool conv = (dxt / xnt) < TOL;   // NaN -> false, matches jnp
        s_conv = conv ? 1.f : 0.f;
        if (conv) solved[row] = 1;
    }
    __syncthreads();
    if (s_conv != 0.f) {
        *(float4*)&enc[off] = make_float4(vn_all[0], vn_all[1], vn_all[2], vn_all[3]);
        *(float4*)&enc[off + 4] = make_float4(vn_all[4], vn_all[5], vn_all[6], vn_all[7]);
    }
}

// ---------------------------------------------------------------------------
extern "C" void kernel_launch(void* const* d_in, const int* in_sizes, int n_in,
                              void* d_out, int out_size, void* d_ws, size_t ws_size,
                              hipStream_t stream) {
    (void)in_sizes; (void)n_in; (void)out_size; (void)ws_size;
    const float* x    = (const float*)d_in[0];   // 1024 x 1024
    const float* w    = (const float*)d_in[1];   // 2048 x 1024
    const float* Minv = (const float*)d_in[2];   // 2048 x 2048

    float* enc = (float*)d_out;                  // 1024 x 2048
    float* dec = enc + (size_t)BATCH * OUT_F;    // 1024 x 1024

    constexpr size_t P = (size_t)BATCH * OUT_F;  // 2M elements
    _Float16* Abh = (_Float16*)d_ws;             // P f16
    _Float16* v   = Abh + P;                     // P f16
    _Float16* u   = v + P;                       // P f16
    fp8_t* Ah  = (fp8_t*)(u + P);                // P fp8
    fp8_t* xkp = Ah + P;                         // 4P fp8
    fp8_t* BhT = xkp + 4 * P;                    // OUT_F^2 fp8 (4MB)
    int* solved = (int*)(BhT + (size_t)OUT_F * OUT_F);

    {
        const int n = BATCH * OUT_F / 4;   // covers enc; v/u need half as many
        init_kernel<<<(n + 255) / 256, 256, 0, stream>>>(
            (float4*)v, (float4*)u, (float4*)enc, solved);
    }

    split_b_kernel<<<dim3(OUT_F / 32, OUT_F / 32), 256, 0, stream>>>(Minv, BhT);

    gemm_nt<<<dim3(OUT_F / BN, BATCH / BM), 256, 0, stream>>>(x, w, Abh, Ah,
                                                              BATCH, OUT_F, IN_F);

    for (int it = 0; it < MAX_ITERS; ++it) {
        xk_mfma<<<dim3(OUT_F / 128, BATCH / 128, KSPLIT), 256, 0, stream>>>(
            Ah, BhT, xkp, solved);
        update_kernel<<<BATCH, 256, 0, stream>>>(xkp, Abh, v, u, enc, Ah, solved);
    }

    gemm_nn<<<dim3(IN_F / BN, BATCH / BM), 256, 0, stream>>>(enc, w, dec, BATCH, IN_F, OUT_F);
}

// Round 9
// 2281.583 us; speedup vs baseline: 5.2132x; 1.0570x over previous
//
#include <hip/hip_runtime.h>
#include <math.h>

#define BATCH 1024
#define IN_F  1024
#define OUT_F 2048
#define LAMBD 0.2f
#define TOL   1e-4f
#define MAX_ITERS 100

#define KSPLIT 4
#define KCHUNK (OUT_F / KSPLIT)   // 512
#define BSCALE 32.0f
#define BSCALE_INV 0.03125f

typedef _Float16 half8 __attribute__((ext_vector_type(8)));
typedef _Float16 half4 __attribute__((ext_vector_type(4)));
typedef float    floatx16 __attribute__((ext_vector_type(16)));
typedef unsigned char fp8_t;

#define GLOAD_LDS16(g, l) __builtin_amdgcn_global_load_lds(              \
    (const __attribute__((address_space(1))) void*)(g),                  \
    (__attribute__((address_space(3))) void*)(l), 16, 0, 0)

// fp8 e4m3 (OCP on gfx950) HW converts
__device__ inline int pk4_fp8(float a, float b, float c, float d) {
    int w = __builtin_amdgcn_cvt_pk_fp8_f32(a, b, 0, false);
    w = __builtin_amdgcn_cvt_pk_fp8_f32(c, d, w, true);
    return w;
}
__device__ inline fp8_t enc_fp8(float a) {
    return (fp8_t)(__builtin_amdgcn_cvt_pk_fp8_f32(a, a, 0, false) & 0xff);
}
// byte-selector must be a literal constant -> expand all four
__device__ inline void cvt4_fp8(int w, float o[4]) {
    o[0] = __builtin_amdgcn_cvt_f32_fp8(w, 0);
    o[1] = __builtin_amdgcn_cvt_f32_fp8(w, 1);
    o[2] = __builtin_amdgcn_cvt_f32_fp8(w, 2);
    o[3] = __builtin_amdgcn_cvt_f32_fp8(w, 3);
}

// ---------------------------------------------------------------------------
// init: zero v,u (fp16), enc (fp32 out), solved flags
// ---------------------------------------------------------------------------
__global__ void init_kernel(float4* __restrict__ v16, float4* __restrict__ u16,
                            float4* __restrict__ enc, int* __restrict__ solved) {
    const int i = blockIdx.x * blockDim.x + threadIdx.x;
    const float4 z = make_float4(0.f, 0.f, 0.f, 0.f);
    const int nh = BATCH * OUT_F / 8;    // v,u as 16B chunks (8 halves)
    const int n4 = BATCH * OUT_F / 4;    // enc as 16B chunks (4 floats)
    if (i < nh) { v16[i] = z; u16[i] = z; }
    if (i < n4) enc[i] = z;
    if (i < BATCH) solved[i] = 0;
}

// ---------------------------------------------------------------------------
// elementwise fp32 -> fp16 cast (n multiple of 4)
// ---------------------------------------------------------------------------
__global__ __launch_bounds__(256)
void cast_f16_kernel(const float* __restrict__ in, _Float16* __restrict__ out, int n) {
    const int i = (blockIdx.x * 256 + threadIdx.x) * 4;
    if (i < n) {
        const float4 f = *(const float4*)&in[i];
        half4 h;
        h[0] = (_Float16)f.x; h[1] = (_Float16)f.y;
        h[2] = (_Float16)f.z; h[3] = (_Float16)f.w;
        *(half4*)&out[i] = h;
    }
}

// ---------------------------------------------------------------------------
// transpose + fp16 cast: W [OUT_F][IN_F] fp32 -> WT [IN_F][OUT_F] fp16
// ---------------------------------------------------------------------------
__global__ __launch_bounds__(256)
void transpose_w_kernel(const float* __restrict__ W, _Float16* __restrict__ WT) {
    __shared__ float tile[32][33];
    const int tid = threadIdx.x;
    const int row0 = blockIdx.y * 32;   // OUT_F dim
    const int col0 = blockIdx.x * 32;   // IN_F dim
    const int r = tid >> 3;
    const int c4 = (tid & 7) * 4;
    const float4 b4 = *(const float4*)&W[(size_t)(row0 + r) * IN_F + col0 + c4];
    tile[r][c4 + 0] = b4.x; tile[r][c4 + 1] = b4.y;
    tile[r][c4 + 2] = b4.z; tile[r][c4 + 3] = b4.w;
    __syncthreads();
    half4 h;
#pragma unroll
    for (int j = 0; j < 4; ++j) h[j] = (_Float16)tile[c4 + j][r];
    *(half4*)&WT[(size_t)(col0 + r) * OUT_F + row0 + c4] = h;
}

// ---------------------------------------------------------------------------
// Transpose + fp8-cast (x32) M_inv (2048x2048 fp32 [k][n]) -> BhT fp8 [n][k].
// ---------------------------------------------------------------------------
__global__ __launch_bounds__(256)
void split_b_kernel(const float* __restrict__ B, fp8_t* __restrict__ BhT) {
    __shared__ float tile[32][33];
    const int tid = threadIdx.x;
    const int k0 = blockIdx.y * 32;
    const int n0 = blockIdx.x * 32;
    const int r = tid >> 3;
    const int c4 = (tid & 7) * 4;
    const float4 b4 = *(const float4*)&B[(size_t)(k0 + r) * OUT_F + n0 + c4];
    tile[r][c4 + 0] = b4.x; tile[r][c4 + 1] = b4.y;
    tile[r][c4 + 2] = b4.z; tile[r][c4 + 3] = b4.w;
    __syncthreads();
    const int w = pk4_fp8(tile[c4 + 0][r] * BSCALE, tile[c4 + 1][r] * BSCALE,
                          tile[c4 + 2][r] * BSCALE, tile[c4 + 3][r] * BSCALE);
    *(int*)&BhT[(size_t)(n0 + r) * OUT_F + k0 + c4] = w;
}

// ---------------------------------------------------------------------------
// fp16 MFMA NT GEMM (one-shot): C = A @ B^T, A [M][K], B [N][K] fp16.
// 128x128 tile, BK=32 (R6-proven pattern). Epilogue -> Abh fp16 + Ah fp8.
// ---------------------------------------------------------------------------
__global__ __launch_bounds__(256)
void mfma_nt_ab(const _Float16* __restrict__ A, const _Float16* __restrict__ B,
                _Float16* __restrict__ Abh, fp8_t* __restrict__ Ah,
                int N, int K) {
    __shared__ _Float16 sA[128 * 32];
    __shared__ _Float16 sB[128 * 32];
    const int tid = threadIdx.x;
    const int m0 = blockIdx.y * 128;
    const int n0 = blockIdx.x * 128;
    const int wv = tid >> 6, ln = tid & 63;
    const int half = ln >> 5, l31 = ln & 31;
    const int wm = (wv >> 1) * 64, wn = (wv & 1) * 64;
    const int r0 = tid >> 2, koff = (tid & 3) * 8;
    const size_t ga0 = (size_t)(m0 + r0) * K + koff;
    const size_t ga1 = (size_t)(m0 + r0 + 64) * K + koff;
    const size_t gb0 = (size_t)(n0 + r0) * K + koff;
    const size_t gb1 = (size_t)(n0 + r0 + 64) * K + koff;
    const int ldst0 = tid * 8, ldst1 = (256 + tid) * 8;

    floatx16 acc[2][2];
#pragma unroll
    for (int a = 0; a < 2; ++a)
#pragma unroll
        for (int b = 0; b < 2; ++b)
#pragma unroll
            for (int q = 0; q < 16; ++q) acc[a][b][q] = 0.f;

    for (int k = 0; k < K; k += 32) {
        __syncthreads();
        GLOAD_LDS16(A + ga0 + k, sA + ldst0);
        GLOAD_LDS16(A + ga1 + k, sA + ldst1);
        GLOAD_LDS16(B + gb0 + k, sB + ldst0);
        GLOAD_LDS16(B + gb1 + k, sB + ldst1);
        __syncthreads();
#pragma unroll
        for (int kk = 0; kk < 2; ++kk) {
            const int ko = kk * 16 + half * 8;
            const half8 a0 = *(const half8*)&sA[(wm + l31) * 32 + ko];
            const half8 a1 = *(const half8*)&sA[(wm + 32 + l31) * 32 + ko];
            const half8 b0 = *(const half8*)&sB[(wn + l31) * 32 + ko];
            const half8 b1 = *(const half8*)&sB[(wn + 32 + l31) * 32 + ko];
            acc[0][0] = __builtin_amdgcn_mfma_f32_32x32x16_f16(a0, b0, acc[0][0], 0, 0, 0);
            acc[0][1] = __builtin_amdgcn_mfma_f32_32x32x16_f16(a0, b1, acc[0][1], 0, 0, 0);
            acc[1][0] = __builtin_amdgcn_mfma_f32_32x32x16_f16(a1, b0, acc[1][0], 0, 0, 0);
            acc[1][1] = __builtin_amdgcn_mfma_f32_32x32x16_f16(a1, b1, acc[1][1], 0, 0, 0);
        }
    }
#pragma unroll
    for (int mm = 0; mm < 2; ++mm)
#pragma unroll
        for (int nn = 0; nn < 2; ++nn) {
            const int col = n0 + wn + nn * 32 + l31;
#pragma unroll
            for (int q = 0; q < 16; ++q) {
                const int row = m0 + wm + mm * 32 + (q & 3) + 8 * (q >> 2) + 4 * half;
                const size_t o = (size_t)row * N + col;
                const float x = acc[mm][nn][q];
                Abh[o] = (_Float16)x;
                Ah[o] = enc_fp8(x);
            }
        }
}

// ---------------------------------------------------------------------------
// fp16 MFMA NT GEMM (one-shot): dec = enc @ w via A=ench [M][K], B=whT [N][K].
// ---------------------------------------------------------------------------
__global__ __launch_bounds__(256)
void mfma_nn_dec(const _Float16* __restrict__ A, const _Float16* __restrict__ B,
                 float* __restrict__ C, int N, int K) {
    __shared__ _Float16 sA[128 * 32];
    __shared__ _Float16 sB[128 * 32];
    const int tid = threadIdx.x;
    const int m0 = blockIdx.y * 128;
    const int n0 = blockIdx.x * 128;
    const int wv = tid >> 6, ln = tid & 63;
    const int half = ln >> 5, l31 = ln & 31;
    const int wm = (wv >> 1) * 64, wn = (wv & 1) * 64;
    const int r0 = tid >> 2, koff = (tid & 3) * 8;
    const size_t ga0 = (size_t)(m0 + r0) * K + koff;
    const size_t ga1 = (size_t)(m0 + r0 + 64) * K + koff;
    const size_t gb0 = (size_t)(n0 + r0) * K + koff;
    const size_t gb1 = (size_t)(n0 + r0 + 64) * K + koff;
    const int ldst0 = tid * 8, ldst1 = (256 + tid) * 8;

    floatx16 acc[2][2];
#pragma unroll
    for (int a = 0; a < 2; ++a)
#pragma unroll
        for (int b = 0; b < 2; ++b)
#pragma unroll
            for (int q = 0; q < 16; ++q) acc[a][b][q] = 0.f;

    for (int k = 0; k < K; k += 32) {
        __syncthreads();
        GLOAD_LDS16(A + ga0 + k, sA + ldst0);
        GLOAD_LDS16(A + ga1 + k, sA + ldst1);
        GLOAD_LDS16(B + gb0 + k, sB + ldst0);
        GLOAD_LDS16(B + gb1 + k, sB + ldst1);
        __syncthreads();
#pragma unroll
        for (int kk = 0; kk < 2; ++kk) {
            const int ko = kk * 16 + half * 8;
            const half8 a0 = *(const half8*)&sA[(wm + l31) * 32 + ko];
            const half8 a1 = *(const half8*)&sA[(wm + 32 + l31) * 32 + ko];
            const half8 b0 = *(const half8*)&sB[(wn + l31) * 32 + ko];
            const half8 b1 = *(const half8*)&sB[(wn + 32 + l31) * 32 + ko];
            acc[0][0] = __builtin_amdgcn_mfma_f32_32x32x16_f16(a0, b0, acc[0][0], 0, 0, 0);
            acc[0][1] = __builtin_amdgcn_mfma_f32_32x32x16_f16(a0, b1, acc[0][1], 0, 0, 0);
            acc[1][0] = __builtin_amdgcn_mfma_f32_32x32x16_f16(a1, b0, acc[1][0], 0, 0, 0);
            acc[1][1] = __builtin_amdgcn_mfma_f32_32x32x16_f16(a1, b1, acc[1][1], 0, 0, 0);
        }
    }
#pragma unroll
    for (int mm = 0; mm < 2; ++mm)
#pragma unroll
        for (int nn = 0; nn < 2; ++nn) {
            const int col = n0 + wn + nn * 32 + l31;
#pragma unroll
            for (int q = 0; q < 16; ++q) {
                const int row = m0 + wm + mm * 32 + (q & 3) + 8 * (q >> 2) + 4 * half;
                C[(size_t)row * N + col] = acc[mm][nn][q];
            }
        }
}

// ---------------------------------------------------------------------------
// fp8 MFMA GEMM: xk_part[kz] = Aeff[:, kz*512...] @ (32*Minv)[kz...] / 32.
// 128x128 tile, BK=64, KSPLIT=4, grid (16,8,4)=512 blocks = 2/CU.
// Column-chunk LDS staging (conflict-free); epilogue transposes through LDS
// for fully-coalesced 16B xkp stores (global layout stays row-major).
// ---------------------------------------------------------------------------
__global__ __launch_bounds__(256)
void xk_mfma(const fp8_t* __restrict__ Ah, const fp8_t* __restrict__ BhT,
             fp8_t* __restrict__ xkp, const int* __restrict__ solved) {
    __shared__ fp8_t smem[16384];
    fp8_t* sA = smem;           // 8KB
    fp8_t* sB = smem + 8192;    // 8KB
    const int tid = threadIdx.x;
    const int m0 = blockIdx.y * 128;
    const int n0 = blockIdx.x * 128;
    const int kz = blockIdx.z;
    constexpr size_t P = (size_t)BATCH * OUT_F;

    __shared__ int s_active;
    if (tid == 0) s_active = 0;
    __syncthreads();
    if (tid < 128 && solved[m0 + tid] == 0) s_active = 1;   // benign race
    __syncthreads();
    if (!s_active) return;

    const int wv = tid >> 6;
    const int ln = tid & 63;
    const int half = ln >> 5;
    const int l31 = ln & 31;
    const int wm = (wv >> 1) * 64;
    const int wn = (wv & 1) * 64;

    const int r = tid & 127;
    const int c0 = tid >> 7;           // 0 or 1
    const fp8_t* gA = Ah  + (size_t)(m0 + r) * OUT_F + kz * KCHUNK;
    const fp8_t* gB = BhT + (size_t)(n0 + r) * OUT_F + kz * KCHUNK;
    fp8_t* lA0 = sA + (c0 * 128 + r) * 16;
    fp8_t* lA1 = sA + ((c0 + 2) * 128 + r) * 16;
    fp8_t* lB0 = sB + (c0 * 128 + r) * 16;
    fp8_t* lB1 = sB + ((c0 + 2) * 128 + r) * 16;

    floatx16 acc[2][2];
#pragma unroll
    for (int a = 0; a < 2; ++a)
#pragma unroll
        for (int b = 0; b < 2; ++b)
#pragma unroll
            for (int q = 0; q < 16; ++q) acc[a][b][q] = 0.f;

    const int ao0 = (wm + l31) * 16 + half * 8;
    const int ao1 = (wm + 32 + l31) * 16 + half * 8;
    const int bo0 = (wn + l31) * 16 + half * 8;
    const int bo1 = (wn + 32 + l31) * 16 + half * 8;

    for (int k = 0; k < KCHUNK; k += 64) {
        __syncthreads();
        GLOAD_LDS16(gA + k + c0 * 16, lA0);
        GLOAD_LDS16(gA + k + (c0 + 2) * 16, lA1);
        GLOAD_LDS16(gB + k + c0 * 16, lB0);
        GLOAD_LDS16(gB + k + (c0 + 2) * 16, lB1);
        __syncthreads();

#pragma unroll
        for (int kk = 0; kk < 4; ++kk) {
            const int cb = kk * 2048;
            const long long a0 = *(const long long*)&sA[cb + ao0];
            const long long a1 = *(const long long*)&sA[cb + ao1];
            const long long b0 = *(const long long*)&sB[cb + bo0];
            const long long b1 = *(const long long*)&sB[cb + bo1];
            acc[0][0] = __builtin_amdgcn_mfma_f32_32x32x16_fp8_fp8(a0, b0, acc[0][0], 0, 0, 0);
            acc[0][1] = __builtin_amdgcn_mfma_f32_32x32x16_fp8_fp8(a0, b1, acc[0][1], 0, 0, 0);
            acc[1][0] = __builtin_amdgcn_mfma_f32_32x32x16_fp8_fp8(a1, b0, acc[1][0], 0, 0, 0);
            acc[1][1] = __builtin_amdgcn_mfma_f32_32x32x16_fp8_fp8(a1, b1, acc[1][1], 0, 0, 0);
        }
    }

    // epilogue: scatter fp8 results into LDS tile, then coalesced 16B stores
    __syncthreads();
#pragma unroll
    for (int mm = 0; mm < 2; ++mm)
#pragma unroll
        for (int nn = 0; nn < 2; ++nn) {
            const int lcol = wn + nn * 32 + l31;
#pragma unroll
            for (int q = 0; q < 16; ++q) {
                const int lrow = wm + mm * 32 + (q & 3) + 8 * (q >> 2) + 4 * half;
                smem[lrow * 128 + lcol] = enc_fp8(acc[mm][nn][q] * BSCALE_INV);
            }
        }
    __syncthreads();
    fp8_t* outp = xkp + kz * P + (size_t)m0 * OUT_F + n0;
#pragma unroll
    for (int s = 0; s < 4; ++s) {
        const int f = (s * 256 + tid) * 16;
        *(int4*)&outp[(size_t)(f >> 7) * OUT_F + (f & 127)] = *(const int4*)&smem[f];
    }
}

// ---------------------------------------------------------------------------
// Update: xk = sum of 4 fp8 partials; softshrink; u update; conv check;
// write next Aeff fp8. One block per row; 8 elements per thread.
// ---------------------------------------------------------------------------
__global__ __launch_bounds__(256)
void update_kernel(const fp8_t* __restrict__ xkp, const _Float16* __restrict__ Abh,
                   _Float16* __restrict__ v, _Float16* __restrict__ u,
                   float* __restrict__ enc, fp8_t* __restrict__ Ah,
                   int* __restrict__ solved) {
    const int row = blockIdx.x;
    if (solved[row]) return;
    const int t = threadIdx.x;
    constexpr size_t P = (size_t)BATCH * OUT_F;

    const int c = t * 8;                      // 256 threads x 8 = 2048 cols
    const size_t off = (size_t)row * OUT_F + c;
    const int2 q0 = *(const int2*)&xkp[off];
    const int2 q1 = *(const int2*)&xkp[P + off];
    const int2 q2 = *(const int2*)&xkp[2 * P + off];
    const int2 q3 = *(const int2*)&xkp[3 * P + off];
    const half8 u8 = *(const half8*)&u[off];
    const half8 v8 = *(const half8*)&v[off];
    const half8 ab8 = *(const half8*)&Abh[off];

    float f0[4], f1[4], f2[4], f3[4], g0[4], g1[4], g2[4], g3[4];
    cvt4_fp8(q0.x, f0); cvt4_fp8(q1.x, f1); cvt4_fp8(q2.x, f2); cvt4_fp8(q3.x, f3);
    cvt4_fp8(q0.y, g0); cvt4_fp8(q1.y, g1); cvt4_fp8(q2.y, g2); cvt4_fp8(q3.y, g3);
    float xs[8];
#pragma unroll
    for (int j = 0; j < 4; ++j) {
        xs[j] = f0[j] + f1[j] + f2[j] + f3[j];
        xs[j + 4] = g0[j] + g1[j] + g2[j] + g3[j];
    }

    float vn_all[8], ae[8];
    half8 vo, uo;
    float dx2 = 0.f, xn2 = 0.f;
#pragma unroll
    for (int j = 0; j < 8; ++j) {
        const float xk = xs[j];
        const float uv = (float)u8[j];
        const float vp = (float)v8[j];
        const float z = xk + uv;
        const float az = fabsf(z) - LAMBD;
        const float vnew = az > 0.f ? copysignf(az, z) : 0.f;
        const float unew = uv + xk - vnew;
        const float d = vnew - vp;
        dx2 += d * d;
        xn2 += vnew * vnew;
        vn_all[j] = vnew;
        vo[j] = (_Float16)vnew;
        uo[j] = (_Float16)unew;
        ae[j] = (float)ab8[j] + vnew - unew;
    }
    *(half8*)&v[off] = vo;
    *(half8*)&u[off] = uo;
    int2 ah;
    ah.x = pk4_fp8(ae[0], ae[1], ae[2], ae[3]);
    ah.y = pk4_fp8(ae[4], ae[5], ae[6], ae[7]);
    *(int2*)&Ah[off] = ah;

#pragma unroll
    for (int o = 32; o > 0; o >>= 1) {
        dx2 += __shfl_down(dx2, o);
        xn2 += __shfl_down(xn2, o);
    }
    __shared__ float sdx[4], sxn[4];
    __shared__ float s_conv;
    if ((t & 63) == 0) { sdx[t >> 6] = dx2; sxn[t >> 6] = xn2; }
    __syncthreads();
    if (t == 0) {
        const float dxt = sqrtf(sdx[0] + sdx[1] + sdx[2] + sdx[3]);
        const float xnt = sqrtf(sxn[0] + sxn[1] + sxn[2] + sxn[3]);
        const bool conv = (dxt / xnt) < TOL;   // NaN -> false, matches jnp
        s_conv = conv ? 1.f : 0.f;
        if (conv) solved[row] = 1;
    }
    __syncthreads();
    if (s_conv != 0.f) {
        *(float4*)&enc[off] = make_float4(vn_all[0], vn_all[1], vn_all[2], vn_all[3]);
        *(float4*)&enc[off + 4] = make_float4(vn_all[4], vn_all[5], vn_all[6], vn_all[7]);
    }
}

// ---------------------------------------------------------------------------
extern "C" void kernel_launch(void* const* d_in, const int* in_sizes, int n_in,
                              void* d_out, int out_size, void* d_ws, size_t ws_size,
                              hipStream_t stream) {
    (void)in_sizes; (void)n_in; (void)out_size; (void)ws_size;
    const float* x    = (const float*)d_in[0];   // 1024 x 1024
    const float* w    = (const float*)d_in[1];   // 2048 x 1024
    const float* Minv = (const float*)d_in[2];   // 2048 x 2048

    float* enc = (float*)d_out;                  // 1024 x 2048
    float* dec = enc + (size_t)BATCH * OUT_F;    // 1024 x 1024

    constexpr size_t P = (size_t)BATCH * OUT_F;  // 2M elements
    _Float16* Abh = (_Float16*)d_ws;             // P f16
    _Float16* v   = Abh + P;                     // P f16
    _Float16* u   = v + P;                       // P f16
    _Float16* xh  = u + P;                       // 1M f16
    _Float16* wh  = xh + (size_t)BATCH * IN_F;   // 2M f16
    _Float16* whT = wh + (size_t)OUT_F * IN_F;   // 2M f16
    _Float16* ench = whT + (size_t)IN_F * OUT_F; // P f16
    fp8_t* Ah  = (fp8_t*)(ench + P);             // P fp8
    fp8_t* xkp = Ah + P;                         // 4P fp8
    fp8_t* BhT = xkp + 4 * P;                    // OUT_F^2 fp8 (4MB)
    int* solved = (int*)(BhT + (size_t)OUT_F * OUT_F);

    {
        const int n = BATCH * OUT_F / 4;
        init_kernel<<<(n + 255) / 256, 256, 0, stream>>>(
            (float4*)v, (float4*)u, (float4*)enc, solved);
    }

    split_b_kernel<<<dim3(OUT_F / 32, OUT_F / 32), 256, 0, stream>>>(Minv, BhT);

    // fp16 casts for the one-shot MFMA GEMMs
    cast_f16_kernel<<<(BATCH * IN_F / 4 + 255) / 256, 256, 0, stream>>>(x, xh, BATCH * IN_F);
    cast_f16_kernel<<<(OUT_F * IN_F / 4 + 255) / 256, 256, 0, stream>>>(w, wh, OUT_F * IN_F);
    transpose_w_kernel<<<dim3(IN_F / 32, OUT_F / 32), 256, 0, stream>>>(w, whT);

    // Ab = x @ w^T (MFMA fp16) -> Abh fp16 + initial Aeff fp8
    mfma_nt_ab<<<dim3(OUT_F / 128, BATCH / 128), 256, 0, stream>>>(
        xh, wh, Abh, Ah, OUT_F, IN_F);

    for (int it = 0; it < MAX_ITERS; ++it) {
        xk_mfma<<<dim3(OUT_F / 128, BATCH / 128, KSPLIT), 256, 0, stream>>>(
            Ah, BhT, xkp, solved);
        update_kernel<<<BATCH, 256, 0, stream>>>(xkp, Abh, v, u, enc, Ah, solved);
    }

    // decoded = encoded @ w (MFMA fp16): cast enc, then NT with whT
    cast_f16_kernel<<<(BATCH * OUT_F / 4 + 255) / 256, 256, 0, stream>>>(enc, ench, BATCH * OUT_F);
    mfma_nn_dec<<<dim3(IN_F / 128, BATCH / 128), 256, 0, stream>>>(
        ench, whT, dec, IN_F, OUT_F);
}